// Round 10
// baseline (1967.896 us; speedup 1.0000x reference)
//
#include <hip/hip_runtime.h>
#include <cstddef>
#include <cstdint>

#define T256 256

typedef __attribute__((ext_vector_type(8))) short bhalf8;
typedef __attribute__((ext_vector_type(4))) float floatx4;

__device__ __forceinline__ ushort f2bf(float f) {
  union { float f; uint32_t u; } v; v.f = f;
  return (ushort)((v.u + 0x7fffu + ((v.u >> 16) & 1u)) >> 16);
}

// ---------------- conv1 (1->16, 7x7, relu, maxpool2) — R10: weights in VGPRs ----------------
__global__ __launch_bounds__(256) void conv1_pool_k(
    const float* __restrict__ x, const float* __restrict__ w,
    const float* __restrict__ bias, float* __restrict__ out)
{
  __shared__ float img[10000];
  __shared__ float wsm[16 * 49];
  __shared__ float bsm[16];
  const int b = blockIdx.x, tid = threadIdx.x;
  for (int i = tid; i < 10000; i += T256) img[i] = x[(size_t)b * 10000 + i];
  for (int i = tid; i < 16 * 49; i += T256) wsm[i] = w[i];
  if (tid < 16) bsm[tid] = bias[tid];
  __syncthreads();
  for (int p = tid; p < 47 * 47; p += T256) {
    const int py = p / 47, px = p % 47;
    const int iy0 = 2 * py, ix0 = 2 * px;
    float win[8][8];
#pragma unroll
    for (int r = 0; r < 8; ++r)
#pragma unroll
      for (int c = 0; c < 8; ++c)
        win[r][c] = img[(iy0 + r) * 100 + (ix0 + c)];
#pragma unroll 1
    for (int oc = 0; oc < 16; ++oc) {
      float wr[49];  // hoist: 49 ds_reads/oc instead of 196 (4 pool reuses from regs)
#pragma unroll
      for (int j = 0; j < 49; ++j) wr[j] = wsm[oc * 49 + j];
      float m = 0.f;
#pragma unroll
      for (int dy = 0; dy < 2; ++dy)
#pragma unroll
        for (int dx = 0; dx < 2; ++dx) {
          float s = bsm[oc];
#pragma unroll
          for (int ky = 0; ky < 7; ++ky)
#pragma unroll
            for (int kx = 0; kx < 7; ++kx)
              s += win[dy + ky][dx + kx] * wr[ky * 7 + kx];
          m = fmaxf(m, s);
        }
      out[((size_t)b * 16 + oc) * 2209 + p] = m;
    }
  }
}

// ---------------- weight pre-swizzle for MFMA convs (proven) ----------------
__global__ __launch_bounds__(256) void wprep_k(
    const float* __restrict__ w, ushort* __restrict__ bswz,
    int IC, int KW, int OC, int total)
{
  const int idx = blockIdx.x * 256 + threadIdx.x;
  if (idx >= total) return;
  const int NT = OC / 16;
  const int lane = idx & 63;
  const int nt = (idx >> 6) % NT;
  const int ks = idx / (64 * NT);
  const int oc = nt * 16 + (lane & 15);
  const int kb = ks * 32 + (lane >> 4) * 8;
  ushort tmp[8];
#pragma unroll
  for (int j = 0; j < 8; ++j) {
    const int k = kb + j;
    const int ic = k % IC, tap = k / IC;
    tmp[j] = f2bf(w[((size_t)oc * IC + ic) * (KW * KW) + tap]);
  }
  *(bhalf8*)(bswz + (size_t)idx * 8) = *(const bhalf8*)tmp;
}

// ---------------- linear-weight pre-swizzle ----------------
__global__ __launch_bounds__(256) void wprep_lin_k(
    const float* __restrict__ w, ushort* __restrict__ bswz,
    int Kdim, int NT, int total)
{
  const int idx = blockIdx.x * 256 + threadIdx.x;
  if (idx >= total) return;
  const int lane = idx & 63;
  const int nt = (idx >> 6) % NT;
  const int ks = idx / (64 * NT);
  const int oc = nt * 16 + (lane & 15);
  const int kb = ks * 32 + (lane >> 4) * 8;
  ushort tmp[8];
#pragma unroll
  for (int j = 0; j < 8; ++j) tmp[j] = f2bf(w[(size_t)oc * Kdim + kb + j]);
  *(bhalf8*)(bswz + (size_t)idx * 8) = *(const bhalf8*)tmp;
}

// ---------------- f32 -> bf16 convert ----------------
__global__ __launch_bounds__(256) void f2bf_k(
    const float* __restrict__ in, ushort* __restrict__ outv, int n)
{
  const int i = (blockIdx.x * 256 + threadIdx.x) * 4;
  if (i >= n) return;
  const float4 v = *(const float4*)&in[i];
  ushort tmp[4] = {f2bf(v.x), f2bf(v.y), f2bf(v.z), f2bf(v.w)};
  *(uint2*)&outv[i] = *(const uint2*)tmp;
}

// ---------------- conv2 MFMA with in-register 2x2 maxpool — unchanged PASS ----------------
__global__ __launch_bounds__(256) void conv2mfma_k(
    const float* __restrict__ in, const ushort* __restrict__ bswz,
    const float* __restrict__ bias, float* __restrict__ out)
{
  constexpr int IC = 16, IH = 47, IW = 47;
  constexpr int NPIX = IH * IW;
  constexpr int ROWU = IC + 8;
  constexpr int KS = 8;
  __shared__ ushort imgT[NPIX * ROWU];
  const int b = blockIdx.x, tid = threadIdx.x;
  const int lane = tid & 63, wv = tid >> 6;

  for (int e = tid; e < IC * NPIX; e += 256) {
    const int ic = e / NPIX, pix = e % NPIX;
    imgT[pix * ROWU + ic] = f2bf(in[((size_t)b * IC + ic) * NPIX + pix]);
  }
  __syncthreads();

  const int col = lane & 15, g = lane >> 4;
  const float b0 = bias[col], b1 = bias[16 + col];

  for (int it = wv; it < 66; it += 4) {
    const int pyp = it / 3, tx = it - pyp * 3;
    int px = tx * 16 + col; px = px < 43 ? px : 43;
    floatx4 acc[2][2];
#pragma unroll
    for (int dy = 0; dy < 2; ++dy)
#pragma unroll
      for (int nt = 0; nt < 2; ++nt) acc[dy][nt] = (floatx4){0.f, 0.f, 0.f, 0.f};

    for (int ks = 0; ks < KS; ++ks) {
      bhalf8 bf[2];
#pragma unroll
      for (int nt = 0; nt < 2; ++nt)
        bf[nt] = *(const bhalf8*)(bswz + ((size_t)(ks * 2 + nt) * 64 + lane) * 8);
      const int kk = ks * 32 + g * 8;
      const int tap = kk >> 4, icb = kk & 15;
      const int ky = tap >> 2, kx = tap & 3;
      bhalf8 af[2];
#pragma unroll
      for (int dy = 0; dy < 2; ++dy)
        af[dy] = *(const bhalf8*)&imgT[((2 * pyp + dy + ky) * IW + px + kx) * ROWU + icb];
#pragma unroll
      for (int dy = 0; dy < 2; ++dy)
#pragma unroll
        for (int nt = 0; nt < 2; ++nt)
          acc[dy][nt] = __builtin_amdgcn_mfma_f32_16x16x32_bf16(
              af[dy], bf[nt], acc[dy][nt], 0, 0, 0);
    }
#pragma unroll
    for (int nt = 0; nt < 2; ++nt) {
      const int oc = nt * 16 + col;
      const float bb = nt ? b1 : b0;
      float vv[4];
#pragma unroll
      for (int i = 0; i < 4; ++i) vv[i] = fmaxf(acc[0][nt][i], acc[1][nt][i]);
#pragma unroll
      for (int q = 0; q < 2; ++q) {
        const int pxp = tx * 8 + g * 2 + q;
        if (pxp < 22) {
          const float v = fmaxf(fmaxf(vv[2 * q], vv[2 * q + 1]) + bb, 0.f);
          out[((size_t)b * 32 + oc) * 484 + pyp * 22 + pxp] = v;
        }
      }
    }
  }
}

// ---------------- MFMA implicit-GEMM conv (+bias+relu) — unchanged PASS ----------------
template <int IC, int IH, int IW, int KW_, int OC, int MC>
__global__ __launch_bounds__(256) void convmfma_k(
    const float* __restrict__ in, const ushort* __restrict__ bswz,
    const float* __restrict__ bias, float* __restrict__ out)
{
  constexpr int OH = IH - KW_ + 1, OW = IW - KW_ + 1, P = OH * OW;
  constexpr int NPIX = IH * IW;
  constexpr int KS = IC * KW_ * KW_ / 32;
  constexpr int NT = OC / 16;
  constexpr int NPW = NT / 4;
  constexpr int MT = (P + 15) / 16;
  constexpr int ROWU = IC + 8;
  static_assert(NT % 4 == 0 && IC % 32 == 0, "cfg");

  __shared__ ushort imgT[NPIX * ROWU];
  const int b = blockIdx.x, tid = threadIdx.x;
  const int lane = tid & 63, wv = tid >> 6;
  const int icoff = (lane >> 4) * 8;

  for (int e = tid; e < IC * NPIX; e += 256) {
    const int ic = e / NPIX, pix = e % NPIX;
    imgT[pix * ROWU + ic] = f2bf(in[((size_t)b * IC + ic) * NPIX + pix]);
  }
  __syncthreads();

  for (int m0 = 0; m0 < MT; m0 += MC) {
    floatx4 acc[MC][NPW];
#pragma unroll
    for (int mi = 0; mi < MC; ++mi)
#pragma unroll
      for (int nn = 0; nn < NPW; ++nn)
        acc[mi][nn] = (floatx4){0.f, 0.f, 0.f, 0.f};

    int pbase[MC];
#pragma unroll
    for (int mi = 0; mi < MC; ++mi) {
      int p = (m0 + mi) * 16 + (lane & 15);
      p = p < P ? p : P - 1;
      pbase[mi] = ((p / OW) * IW + (p % OW)) * ROWU;
    }

    bhalf8 bcur[NPW];
#pragma unroll
    for (int nn = 0; nn < NPW; ++nn)
      bcur[nn] = *(const bhalf8*)(bswz + ((size_t)(wv * NPW + nn) * 64 + lane) * 8);

    for (int ks = 0; ks < KS; ++ks) {
      bhalf8 bnext[NPW];
      if (ks + 1 < KS) {
#pragma unroll
        for (int nn = 0; nn < NPW; ++nn)
          bnext[nn] = *(const bhalf8*)(bswz +
              ((size_t)((ks + 1) * NT + wv * NPW + nn) * 64 + lane) * 8);
      }
      const int tap = (ks * 32) / IC;
      const int icb = (ks * 32) % IC;
      const int aoff = ((tap / KW_) * IW + (tap % KW_)) * ROWU + icb + icoff;
      bhalf8 af[MC];
#pragma unroll
      for (int mi = 0; mi < MC; ++mi)
        af[mi] = *(const bhalf8*)&imgT[pbase[mi] + aoff];
#pragma unroll
      for (int mi = 0; mi < MC; ++mi)
#pragma unroll
        for (int nn = 0; nn < NPW; ++nn)
          acc[mi][nn] = __builtin_amdgcn_mfma_f32_16x16x32_bf16(
              af[mi], bcur[nn], acc[mi][nn], 0, 0, 0);
      if (ks + 1 < KS) {
#pragma unroll
        for (int nn = 0; nn < NPW; ++nn) bcur[nn] = bnext[nn];
      }
    }
#pragma unroll
    for (int mi = 0; mi < MC; ++mi)
#pragma unroll
      for (int nn = 0; nn < NPW; ++nn) {
        const int oc = (wv * NPW + nn) * 16 + (lane & 15);
#pragma unroll
        for (int i = 0; i < 4; ++i) {
          const int p = (m0 + mi) * 16 + (lane >> 4) * 4 + i;
          if (p < P) {
            const float v = fmaxf(acc[mi][nn][i] + bias[oc], 0.f);
            out[((size_t)b * OC + oc) * P + p] = v;
          }
        }
      }
  }
}

// ---------------- bf16 MFMA GEMM (linear1) — unchanged PASS ----------------
__global__ __launch_bounds__(256) void gemm_bf16_k(
    const ushort* __restrict__ abf, const ushort* __restrict__ bswz,
    const float* __restrict__ bias, float* __restrict__ C,
    int M, int N, int K)
{
  __shared__ ushort As[64][72];
  const int bn = blockIdx.x, bm = blockIdx.y, tid = threadIdx.x;
  const int lane = tid & 63, wv = tid >> 6;
  const int m0 = bm * 64, n0 = bn * 64;
  const int NTg = N / 16;
  const int ntg = bn * 4 + wv;
  floatx4 acc[4];
#pragma unroll
  for (int mt = 0; mt < 4; ++mt) acc[mt] = (floatx4){0.f, 0.f, 0.f, 0.f};

  for (int kc = 0; kc < K / 64; ++kc) {
    __syncthreads();
#pragma unroll
    for (int q = 0; q < 2; ++q) {
      const int id = q * 256 + tid;
      const int row = id >> 3, kcol = (id & 7) * 8;
      *(bhalf8*)&As[row][kcol] =
          *(const bhalf8*)&abf[(size_t)(m0 + row) * K + kc * 64 + kcol];
    }
    __syncthreads();
#pragma unroll
    for (int k2 = 0; k2 < 2; ++k2) {
      const int ks = kc * 2 + k2;
      const bhalf8 bf = *(const bhalf8*)(bswz + ((size_t)(ks * NTg + ntg) * 64 + lane) * 8);
      const int ksub = k2 * 32 + (lane >> 4) * 8;
#pragma unroll
      for (int mt = 0; mt < 4; ++mt) {
        const bhalf8 af = *(const bhalf8*)&As[mt * 16 + (lane & 15)][ksub];
        acc[mt] = __builtin_amdgcn_mfma_f32_16x16x32_bf16(af, bf, acc[mt], 0, 0, 0);
      }
    }
  }
  const int n = n0 + wv * 16 + (lane & 15);
  const float bb = bias[n];
#pragma unroll
  for (int mt = 0; mt < 4; ++mt)
#pragma unroll
    for (int i = 0; i < 4; ++i) {
      const int m = m0 + mt * 16 + (lane >> 4) * 4 + i;
      C[(size_t)m * N + n] = acc[mt][i] + bb;
    }
}

// ---------------- fp32 tiled GEMM (linear2, gin) — unchanged PASS ----------------
template <int ACT>
__global__ __launch_bounds__(256) void gemm_tn_k(
    const float* __restrict__ A, const float* __restrict__ B,
    const float* __restrict__ b1, const float* __restrict__ b2,
    float* __restrict__ C, int M, int N, int K)
{
  __shared__ float As[32][66];
  __shared__ float Bs[32][36];
  const int bn = blockIdx.x, bm = blockIdx.y, tid = threadIdx.x;
  const int tx = tid & 7, ty = tid >> 3;
  const int m0 = bm * 64, n0 = bn * 32;
  double acc[2][4] = {{0, 0, 0, 0}, {0, 0, 0, 0}};
  for (int k0 = 0; k0 < K; k0 += 32) {
    __syncthreads();
#pragma unroll
    for (int l = 0; l < 8; ++l) {
      int id = tid + l * 256;
      int kk = id & 31, mm = id >> 5;
      As[kk][mm] = A[(size_t)(m0 + mm) * K + (k0 + kk)];
    }
#pragma unroll
    for (int l = 0; l < 4; ++l) {
      int id = tid + l * 256;
      int kk = id & 31, nn = id >> 5;
      Bs[kk][nn] = B[(size_t)(n0 + nn) * K + (k0 + kk)];
    }
    __syncthreads();
    float p[2][4] = {{0.f, 0.f, 0.f, 0.f}, {0.f, 0.f, 0.f, 0.f}};
#pragma unroll
    for (int kk = 0; kk < 32; ++kk) {
      const float2 av = *reinterpret_cast<const float2*>(&As[kk][ty * 2]);
      const float4 bv = *reinterpret_cast<const float4*>(&Bs[kk][tx * 4]);
      p[0][0] += av.x * bv.x; p[0][1] += av.x * bv.y;
      p[0][2] += av.x * bv.z; p[0][3] += av.x * bv.w;
      p[1][0] += av.y * bv.x; p[1][1] += av.y * bv.y;
      p[1][2] += av.y * bv.z; p[1][3] += av.y * bv.w;
    }
#pragma unroll
    for (int i = 0; i < 2; ++i)
#pragma unroll
      for (int j = 0; j < 4; ++j) acc[i][j] += (double)p[i][j];
  }
#pragma unroll
  for (int i = 0; i < 2; ++i) {
    const int m = m0 + ty * 2 + i;
#pragma unroll
    for (int j = 0; j < 4; ++j) {
      const int n = n0 + tx * 4 + j;
      double v = acc[i][j] + (double)b1[n];
      if (b2) v += (double)b2[n];
      if (ACT == 1) v = 1.0 / (1.0 + exp(-v));
      C[(size_t)m * N + n] = (float)v;
    }
  }
}

// ---------------- persistent LSTM (R10: column-owning waves, 1 barrier/step) ----------------
// 16 WGs x 24 cols, 768t = 12 waves. Wave = 2 cols x {4 gates x 8 sub-lanes}.
// Lane l: ch=l>>5 (col half), gate=(l>>3)&3, sub=l&7; col = wg*24 + w*2 + ch.
// After 8-lane shfl reduce, the 4 gate sums for a column are IN-WAVE -> 3 shfl
// gather, gate math on lane (l&31)==0, no gsum LDS, no second barrier.
// hsm double-buffered [2][8][52]; end-barrier elided (staging(t+2) transitively
// waits on this WG's own laggard wave via its tagged(t+1) store).
#define NWG 16
#define CPW 24
__global__ __launch_bounds__(768) void lstm_k(
    const float* __restrict__ gin, const float* __restrict__ whh,
    float* __restrict__ out, unsigned long long* __restrict__ tagged)
{
  __shared__ __align__(16) float hsm[2][8][52];
  const int wg = blockIdx.x, tid = threadIdx.x;
  const int w = tid >> 6, l = tid & 63;
  const int ch = l >> 5, gate = (l >> 3) & 3, sub = l & 7;
  const int col = wg * CPW + w * 2 + ch;
  float wreg[48];
  {
    const float* wr = whh + ((size_t)gate * 384 + col) * 384 + sub * 48;
#pragma unroll
    for (int i = 0; i < 48; ++i) wreg[i] = wr[i];
  }
  float c = 0.f;  // cell state (lanes l&31==0)
  __syncthreads();
  for (int t = 0; t < 512; ++t) {
    // gin prefetch by gate leaders (independent of h)
    float ginv = 0.f;
    if (sub == 0) ginv = gin[(size_t)t * 1536 + gate * 384 + col];
    // stage h(t-1) into buffer t&1
    if (tid < 384) {
      float hv;
      if (t == 0) {
        hv = 0.f;
      } else {
        unsigned long long u;
        do {
          u = __hip_atomic_load(&tagged[(size_t)(t - 1) * 384 + tid],
                                __ATOMIC_RELAXED, __HIP_MEMORY_SCOPE_AGENT);
        } while ((unsigned)(u >> 32) != (unsigned)t);
        union { unsigned ui; float f; } cv; cv.ui = (unsigned)u; hv = cv.f;
      }
      hsm[t & 1][tid / 48][tid % 48] = hv;
    }
    __syncthreads();
    // 48-elem dot for (gate,col) sub-chunk
    float s = 0.f;
    {
      const float4* hp = (const float4*)&hsm[t & 1][sub][0];
#pragma unroll
      for (int q = 0; q < 12; ++q) {
        const float4 hv = hp[q];
        s += wreg[4 * q + 0] * hv.x + wreg[4 * q + 1] * hv.y
           + wreg[4 * q + 2] * hv.z + wreg[4 * q + 3] * hv.w;
      }
    }
    s += __shfl_xor(s, 1);
    s += __shfl_xor(s, 2);
    s += __shfl_xor(s, 4);
    const float sg = s + ginv;          // full gate pre-activation at sub==0 lanes
    const int base = l & 32;
    const float gi = __shfl(sg, base);
    const float gf = __shfl(sg, base + 8);
    const float gg = __shfl(sg, base + 16);
    const float go = __shfl(sg, base + 24);
    if ((l & 31) == 0) {
      const float si = 1.f / (1.f + expf(-gi));
      const float sf = 1.f / (1.f + expf(-gf));
      const float so = 1.f / (1.f + expf(-go));
      c = sf * c + si * tanhf(gg);
      const float hn = so * tanhf(c);
      union { float f; unsigned ui; } cv; cv.f = hn;
      const unsigned long long pk = ((unsigned long long)(t + 1) << 32) | cv.ui;
      __hip_atomic_store(&tagged[(size_t)t * 384 + col], pk,
                         __ATOMIC_RELAXED, __HIP_MEMORY_SCOPE_AGENT);
      out[(size_t)t * 384 + col] = hn;
    }
    // no end barrier: hsm double-buffered; see header comment for safety chain
  }
}

extern "C" void kernel_launch(void* const* d_in, const int* in_sizes, int n_in,
                              void* d_out, int out_size, void* d_ws, size_t ws_size,
                              hipStream_t stream)
{
  const float* x   = (const float*)d_in[0];
  const float* cw1 = (const float*)d_in[1];
  const float* cb1 = (const float*)d_in[2];
  const float* cw2 = (const float*)d_in[3];
  const float* cb2 = (const float*)d_in[4];
  const float* cw3 = (const float*)d_in[5];
  const float* cb3 = (const float*)d_in[6];
  const float* cw4 = (const float*)d_in[7];
  const float* cb4 = (const float*)d_in[8];
  const float* cw5 = (const float*)d_in[9];
  const float* cb5 = (const float*)d_in[10];
  const float* cw6 = (const float*)d_in[11];
  const float* cb6 = (const float*)d_in[12];
  const float* lw1 = (const float*)d_in[13];
  const float* lb1 = (const float*)d_in[14];
  const float* lw2 = (const float*)d_in[15];
  const float* lb2 = (const float*)d_in[16];
  const float* wih = (const float*)d_in[17];
  const float* whh = (const float*)d_in[18];
  const float* bih = (const float*)d_in[19];
  const float* bhh = (const float*)d_in[20];
  float* out = (float*)d_out;
  char* ws = (char*)d_ws;

  // workspace layout (R3-fixed, proven)
  float* bufA = (float*)(ws);                       // 72.4 MB conv ping
  float* bufB = (float*)(ws + 72384512);            // 51.4 MB conv pong
  float* l1o  = (float*)(ws + 123764736);           // 2 MB
  float* x2   = (float*)(ws + 125861888);
  float* gin  = (float*)(ws + 126648320);
  // conv bswz weights in l1o region (dead until linear1 output overwrites):
  ushort* bw3 = (ushort*)(ws + 123764736);
  ushort* bw4 = (ushort*)(ws + 123764736 + 102400);
  ushort* bw5 = (ushort*)(ws + 123764736 + 512000);
  ushort* bw6 = (ushort*)(ws + 123764736 + 1331200);
  ushort* bw2 = (ushort*)(ws + 123764736 + 1626112);
  // post-conv6 scratch inside then-dead bufA region:
  ushort* bw1 = (ushort*)(ws);                      // 16.8 MB swizzled lw1 bf16
  ushort* abf = (ushort*)(ws + 16777216);           // 8.4 MB conv6-out bf16
  unsigned long long* tagged = (unsigned long long*)(ws + 25165824);  // 1.57 MB

  // conv weight pre-swizzles (l1o region free until linear1)
  wprep_k<<<(25 * 4 * 64 + 255) / 256, 256, 0, stream>>>(cw3, bw3, 32, 5, 64, 25 * 4 * 64);
  wprep_k<<<(50 * 8 * 64 + 255) / 256, 256, 0, stream>>>(cw4, bw4, 64, 5, 128, 50 * 8 * 64);
  wprep_k<<<(100 * 8 * 64 + 255) / 256, 256, 0, stream>>>(cw5, bw5, 128, 5, 128, 100 * 8 * 64);
  wprep_k<<<(36 * 8 * 64 + 255) / 256, 256, 0, stream>>>(cw6, bw6, 128, 3, 128, 36 * 8 * 64);
  wprep_k<<<(8 * 2 * 64 + 255) / 256, 256, 0, stream>>>(cw2, bw2, 16, 4, 32, 8 * 2 * 64);

  conv1_pool_k<<<512, 256, 0, stream>>>(x, cw1, cb1, bufA);
  conv2mfma_k<<<512, 256, 0, stream>>>(bufA, bw2, cb2, bufB);
  convmfma_k<32, 22, 22, 5, 64, 7><<<512, 256, 0, stream>>>(bufB, bw3, cb3, bufA);
  convmfma_k<64, 18, 18, 5, 128, 7><<<512, 256, 0, stream>>>(bufA, bw4, cb4, bufB);
  convmfma_k<128, 14, 14, 5, 128, 7><<<512, 256, 0, stream>>>(bufB, bw5, cb5, bufA);
  convmfma_k<128, 10, 10, 3, 128, 4><<<512, 256, 0, stream>>>(bufA, bw6, cb6, bufB);
  // bufA now dead -> linear1 scratch + tagged live there
  wprep_lin_k<<<(256 * 64 * 64 + 255) / 256, 256, 0, stream>>>(lw1, bw1, 8192, 64, 256 * 64 * 64);
  f2bf_k<<<(512 * 8192 / 4 + 255) / 256, 256, 0, stream>>>(bufB, abf, 512 * 8192);
  hipMemsetAsync(tagged, 0, 512 * 384 * 8, stream);
  gemm_bf16_k<<<dim3(16, 8), 256, 0, stream>>>(abf, bw1, lb1, l1o, 512, 1024, 8192);
  gemm_tn_k<1><<<dim3(384 / 32, 512 / 64), 256, 0, stream>>>(l1o, lw2, lb2, nullptr, x2, 512, 384, 1024);
  gemm_tn_k<0><<<dim3(1536 / 32, 512 / 64), 256, 0, stream>>>(x2, wih, bih, bhh, gin, 512, 1536, 384);
  lstm_k<<<NWG, 768, 0, stream>>>(gin, whh, out, tagged);
}

// Round 11
// 1510.458 us; speedup vs baseline: 1.3028x; 1.3028x over previous
//
#include <hip/hip_runtime.h>
#include <cstddef>
#include <cstdint>

#define T256 256

typedef __attribute__((ext_vector_type(8))) short bhalf8;
typedef __attribute__((ext_vector_type(4))) float floatx4;

__device__ __forceinline__ ushort f2bf(float f) {
  union { float f; uint32_t u; } v; v.f = f;
  return (ushort)((v.u + 0x7fffu + ((v.u >> 16) & 1u)) >> 16);
}

// ---------------- conv1 (1->16, 7x7, relu, maxpool2) — weights in VGPRs (R10 win) ----------------
__global__ __launch_bounds__(256) void conv1_pool_k(
    const float* __restrict__ x, const float* __restrict__ w,
    const float* __restrict__ bias, float* __restrict__ out)
{
  __shared__ float img[10000];
  __shared__ float wsm[16 * 49];
  __shared__ float bsm[16];
  const int b = blockIdx.x, tid = threadIdx.x;
  for (int i = tid; i < 10000; i += T256) img[i] = x[(size_t)b * 10000 + i];
  for (int i = tid; i < 16 * 49; i += T256) wsm[i] = w[i];
  if (tid < 16) bsm[tid] = bias[tid];
  __syncthreads();
  for (int p = tid; p < 47 * 47; p += T256) {
    const int py = p / 47, px = p % 47;
    const int iy0 = 2 * py, ix0 = 2 * px;
    float win[8][8];
#pragma unroll
    for (int r = 0; r < 8; ++r)
#pragma unroll
      for (int c = 0; c < 8; ++c)
        win[r][c] = img[(iy0 + r) * 100 + (ix0 + c)];
#pragma unroll 1
    for (int oc = 0; oc < 16; ++oc) {
      float wr[49];
#pragma unroll
      for (int j = 0; j < 49; ++j) wr[j] = wsm[oc * 49 + j];
      float m = 0.f;
#pragma unroll
      for (int dy = 0; dy < 2; ++dy)
#pragma unroll
        for (int dx = 0; dx < 2; ++dx) {
          float s = bsm[oc];
#pragma unroll
          for (int ky = 0; ky < 7; ++ky)
#pragma unroll
            for (int kx = 0; kx < 7; ++kx)
              s += win[dy + ky][dx + kx] * wr[ky * 7 + kx];
          m = fmaxf(m, s);
        }
      out[((size_t)b * 16 + oc) * 2209 + p] = m;
    }
  }
}

// ---------------- weight pre-swizzle for MFMA convs (proven) ----------------
__global__ __launch_bounds__(256) void wprep_k(
    const float* __restrict__ w, ushort* __restrict__ bswz,
    int IC, int KW, int OC, int total)
{
  const int idx = blockIdx.x * 256 + threadIdx.x;
  if (idx >= total) return;
  const int NT = OC / 16;
  const int lane = idx & 63;
  const int nt = (idx >> 6) % NT;
  const int ks = idx / (64 * NT);
  const int oc = nt * 16 + (lane & 15);
  const int kb = ks * 32 + (lane >> 4) * 8;
  ushort tmp[8];
#pragma unroll
  for (int j = 0; j < 8; ++j) {
    const int k = kb + j;
    const int ic = k % IC, tap = k / IC;
    tmp[j] = f2bf(w[((size_t)oc * IC + ic) * (KW * KW) + tap]);
  }
  *(bhalf8*)(bswz + (size_t)idx * 8) = *(const bhalf8*)tmp;
}

// ---------------- linear-weight pre-swizzle ----------------
__global__ __launch_bounds__(256) void wprep_lin_k(
    const float* __restrict__ w, ushort* __restrict__ bswz,
    int Kdim, int NT, int total)
{
  const int idx = blockIdx.x * 256 + threadIdx.x;
  if (idx >= total) return;
  const int lane = idx & 63;
  const int nt = (idx >> 6) % NT;
  const int ks = idx / (64 * NT);
  const int oc = nt * 16 + (lane & 15);
  const int kb = ks * 32 + (lane >> 4) * 8;
  ushort tmp[8];
#pragma unroll
  for (int j = 0; j < 8; ++j) tmp[j] = f2bf(w[(size_t)oc * Kdim + kb + j]);
  *(bhalf8*)(bswz + (size_t)idx * 8) = *(const bhalf8*)tmp;
}

// ---------------- f32 -> bf16 convert ----------------
__global__ __launch_bounds__(256) void f2bf_k(
    const float* __restrict__ in, ushort* __restrict__ outv, int n)
{
  const int i = (blockIdx.x * 256 + threadIdx.x) * 4;
  if (i >= n) return;
  const float4 v = *(const float4*)&in[i];
  ushort tmp[4] = {f2bf(v.x), f2bf(v.y), f2bf(v.z), f2bf(v.w)};
  *(uint2*)&outv[i] = *(const uint2*)tmp;
}

// ---------------- conv2 MFMA with in-register 2x2 maxpool — unchanged PASS ----------------
__global__ __launch_bounds__(256) void conv2mfma_k(
    const float* __restrict__ in, const ushort* __restrict__ bswz,
    const float* __restrict__ bias, float* __restrict__ out)
{
  constexpr int IC = 16, IH = 47, IW = 47;
  constexpr int NPIX = IH * IW;
  constexpr int ROWU = IC + 8;
  constexpr int KS = 8;
  __shared__ ushort imgT[NPIX * ROWU];
  const int b = blockIdx.x, tid = threadIdx.x;
  const int lane = tid & 63, wv = tid >> 6;

  for (int e = tid; e < IC * NPIX; e += 256) {
    const int ic = e / NPIX, pix = e % NPIX;
    imgT[pix * ROWU + ic] = f2bf(in[((size_t)b * IC + ic) * NPIX + pix]);
  }
  __syncthreads();

  const int col = lane & 15, g = lane >> 4;
  const float b0 = bias[col], b1 = bias[16 + col];

  for (int it = wv; it < 66; it += 4) {
    const int pyp = it / 3, tx = it - pyp * 3;
    int px = tx * 16 + col; px = px < 43 ? px : 43;
    floatx4 acc[2][2];
#pragma unroll
    for (int dy = 0; dy < 2; ++dy)
#pragma unroll
      for (int nt = 0; nt < 2; ++nt) acc[dy][nt] = (floatx4){0.f, 0.f, 0.f, 0.f};

    for (int ks = 0; ks < KS; ++ks) {
      bhalf8 bf[2];
#pragma unroll
      for (int nt = 0; nt < 2; ++nt)
        bf[nt] = *(const bhalf8*)(bswz + ((size_t)(ks * 2 + nt) * 64 + lane) * 8);
      const int kk = ks * 32 + g * 8;
      const int tap = kk >> 4, icb = kk & 15;
      const int ky = tap >> 2, kx = tap & 3;
      bhalf8 af[2];
#pragma unroll
      for (int dy = 0; dy < 2; ++dy)
        af[dy] = *(const bhalf8*)&imgT[((2 * pyp + dy + ky) * IW + px + kx) * ROWU + icb];
#pragma unroll
      for (int dy = 0; dy < 2; ++dy)
#pragma unroll
        for (int nt = 0; nt < 2; ++nt)
          acc[dy][nt] = __builtin_amdgcn_mfma_f32_16x16x32_bf16(
              af[dy], bf[nt], acc[dy][nt], 0, 0, 0);
    }
#pragma unroll
    for (int nt = 0; nt < 2; ++nt) {
      const int oc = nt * 16 + col;
      const float bb = nt ? b1 : b0;
      float vv[4];
#pragma unroll
      for (int i = 0; i < 4; ++i) vv[i] = fmaxf(acc[0][nt][i], acc[1][nt][i]);
#pragma unroll
      for (int q = 0; q < 2; ++q) {
        const int pxp = tx * 8 + g * 2 + q;
        if (pxp < 22) {
          const float v = fmaxf(fmaxf(vv[2 * q], vv[2 * q + 1]) + bb, 0.f);
          out[((size_t)b * 32 + oc) * 484 + pyp * 22 + pxp] = v;
        }
      }
    }
  }
}

// ---------------- MFMA implicit-GEMM conv (+bias+relu) — unchanged PASS ----------------
template <int IC, int IH, int IW, int KW_, int OC, int MC>
__global__ __launch_bounds__(256) void convmfma_k(
    const float* __restrict__ in, const ushort* __restrict__ bswz,
    const float* __restrict__ bias, float* __restrict__ out)
{
  constexpr int OH = IH - KW_ + 1, OW = IW - KW_ + 1, P = OH * OW;
  constexpr int NPIX = IH * IW;
  constexpr int KS = IC * KW_ * KW_ / 32;
  constexpr int NT = OC / 16;
  constexpr int NPW = NT / 4;
  constexpr int MT = (P + 15) / 16;
  constexpr int ROWU = IC + 8;
  static_assert(NT % 4 == 0 && IC % 32 == 0, "cfg");

  __shared__ ushort imgT[NPIX * ROWU];
  const int b = blockIdx.x, tid = threadIdx.x;
  const int lane = tid & 63, wv = tid >> 6;
  const int icoff = (lane >> 4) * 8;

  for (int e = tid; e < IC * NPIX; e += 256) {
    const int ic = e / NPIX, pix = e % NPIX;
    imgT[pix * ROWU + ic] = f2bf(in[((size_t)b * IC + ic) * NPIX + pix]);
  }
  __syncthreads();

  for (int m0 = 0; m0 < MT; m0 += MC) {
    floatx4 acc[MC][NPW];
#pragma unroll
    for (int mi = 0; mi < MC; ++mi)
#pragma unroll
      for (int nn = 0; nn < NPW; ++nn)
        acc[mi][nn] = (floatx4){0.f, 0.f, 0.f, 0.f};

    int pbase[MC];
#pragma unroll
    for (int mi = 0; mi < MC; ++mi) {
      int p = (m0 + mi) * 16 + (lane & 15);
      p = p < P ? p : P - 1;
      pbase[mi] = ((p / OW) * IW + (p % OW)) * ROWU;
    }

    bhalf8 bcur[NPW];
#pragma unroll
    for (int nn = 0; nn < NPW; ++nn)
      bcur[nn] = *(const bhalf8*)(bswz + ((size_t)(wv * NPW + nn) * 64 + lane) * 8);

    for (int ks = 0; ks < KS; ++ks) {
      bhalf8 bnext[NPW];
      if (ks + 1 < KS) {
#pragma unroll
        for (int nn = 0; nn < NPW; ++nn)
          bnext[nn] = *(const bhalf8*)(bswz +
              ((size_t)((ks + 1) * NT + wv * NPW + nn) * 64 + lane) * 8);
      }
      const int tap = (ks * 32) / IC;
      const int icb = (ks * 32) % IC;
      const int aoff = ((tap / KW_) * IW + (tap % KW_)) * ROWU + icb + icoff;
      bhalf8 af[MC];
#pragma unroll
      for (int mi = 0; mi < MC; ++mi)
        af[mi] = *(const bhalf8*)&imgT[pbase[mi] + aoff];
#pragma unroll
      for (int mi = 0; mi < MC; ++mi)
#pragma unroll
        for (int nn = 0; nn < NPW; ++nn)
          acc[mi][nn] = __builtin_amdgcn_mfma_f32_16x16x32_bf16(
              af[mi], bcur[nn], acc[mi][nn], 0, 0, 0);
      if (ks + 1 < KS) {
#pragma unroll
        for (int nn = 0; nn < NPW; ++nn) bcur[nn] = bnext[nn];
      }
    }
#pragma unroll
    for (int mi = 0; mi < MC; ++mi)
#pragma unroll
      for (int nn = 0; nn < NPW; ++nn) {
        const int oc = (wv * NPW + nn) * 16 + (lane & 15);
#pragma unroll
        for (int i = 0; i < 4; ++i) {
          const int p = (m0 + mi) * 16 + (lane >> 4) * 4 + i;
          if (p < P) {
            const float v = fmaxf(acc[mi][nn][i] + bias[oc], 0.f);
            out[((size_t)b * OC + oc) * P + p] = v;
          }
        }
      }
  }
}

// ---------------- bf16 MFMA GEMM (linear1) — unchanged PASS ----------------
__global__ __launch_bounds__(256) void gemm_bf16_k(
    const ushort* __restrict__ abf, const ushort* __restrict__ bswz,
    const float* __restrict__ bias, float* __restrict__ C,
    int M, int N, int K)
{
  __shared__ ushort As[64][72];
  const int bn = blockIdx.x, bm = blockIdx.y, tid = threadIdx.x;
  const int lane = tid & 63, wv = tid >> 6;
  const int m0 = bm * 64, n0 = bn * 64;
  const int NTg = N / 16;
  const int ntg = bn * 4 + wv;
  floatx4 acc[4];
#pragma unroll
  for (int mt = 0; mt < 4; ++mt) acc[mt] = (floatx4){0.f, 0.f, 0.f, 0.f};

  for (int kc = 0; kc < K / 64; ++kc) {
    __syncthreads();
#pragma unroll
    for (int q = 0; q < 2; ++q) {
      const int id = q * 256 + tid;
      const int row = id >> 3, kcol = (id & 7) * 8;
      *(bhalf8*)&As[row][kcol] =
          *(const bhalf8*)&abf[(size_t)(m0 + row) * K + kc * 64 + kcol];
    }
    __syncthreads();
#pragma unroll
    for (int k2 = 0; k2 < 2; ++k2) {
      const int ks = kc * 2 + k2;
      const bhalf8 bf = *(const bhalf8*)(bswz + ((size_t)(ks * NTg + ntg) * 64 + lane) * 8);
      const int ksub = k2 * 32 + (lane >> 4) * 8;
#pragma unroll
      for (int mt = 0; mt < 4; ++mt) {
        const bhalf8 af = *(const bhalf8*)&As[mt * 16 + (lane & 15)][ksub];
        acc[mt] = __builtin_amdgcn_mfma_f32_16x16x32_bf16(af, bf, acc[mt], 0, 0, 0);
      }
    }
  }
  const int n = n0 + wv * 16 + (lane & 15);
  const float bb = bias[n];
#pragma unroll
  for (int mt = 0; mt < 4; ++mt)
#pragma unroll
    for (int i = 0; i < 4; ++i) {
      const int m = m0 + mt * 16 + (lane >> 4) * 4 + i;
      C[(size_t)m * N + n] = acc[mt][i] + bb;
    }
}

// ---------------- fp32 tiled GEMM (linear2, gin) — unchanged PASS ----------------
template <int ACT>
__global__ __launch_bounds__(256) void gemm_tn_k(
    const float* __restrict__ A, const float* __restrict__ B,
    const float* __restrict__ b1, const float* __restrict__ b2,
    float* __restrict__ C, int M, int N, int K)
{
  __shared__ float As[32][66];
  __shared__ float Bs[32][36];
  const int bn = blockIdx.x, bm = blockIdx.y, tid = threadIdx.x;
  const int tx = tid & 7, ty = tid >> 3;
  const int m0 = bm * 64, n0 = bn * 32;
  double acc[2][4] = {{0, 0, 0, 0}, {0, 0, 0, 0}};
  for (int k0 = 0; k0 < K; k0 += 32) {
    __syncthreads();
#pragma unroll
    for (int l = 0; l < 8; ++l) {
      int id = tid + l * 256;
      int kk = id & 31, mm = id >> 5;
      As[kk][mm] = A[(size_t)(m0 + mm) * K + (k0 + kk)];
    }
#pragma unroll
    for (int l = 0; l < 4; ++l) {
      int id = tid + l * 256;
      int kk = id & 31, nn = id >> 5;
      Bs[kk][nn] = B[(size_t)(n0 + nn) * K + (k0 + kk)];
    }
    __syncthreads();
    float p[2][4] = {{0.f, 0.f, 0.f, 0.f}, {0.f, 0.f, 0.f, 0.f}};
#pragma unroll
    for (int kk = 0; kk < 32; ++kk) {
      const float2 av = *reinterpret_cast<const float2*>(&As[kk][ty * 2]);
      const float4 bv = *reinterpret_cast<const float4*>(&Bs[kk][tx * 4]);
      p[0][0] += av.x * bv.x; p[0][1] += av.x * bv.y;
      p[0][2] += av.x * bv.z; p[0][3] += av.x * bv.w;
      p[1][0] += av.y * bv.x; p[1][1] += av.y * bv.y;
      p[1][2] += av.y * bv.z; p[1][3] += av.y * bv.w;
    }
#pragma unroll
    for (int i = 0; i < 2; ++i)
#pragma unroll
      for (int j = 0; j < 4; ++j) acc[i][j] += (double)p[i][j];
  }
#pragma unroll
  for (int i = 0; i < 2; ++i) {
    const int m = m0 + ty * 2 + i;
#pragma unroll
    for (int j = 0; j < 4; ++j) {
      const int n = n0 + tx * 4 + j;
      double v = acc[i][j] + (double)b1[n];
      if (b2) v += (double)b2[n];
      if (ACT == 1) v = 1.0 / (1.0 + exp(-v));
      C[(size_t)m * N + n] = (float)v;
    }
  }
}

// ---------------- persistent LSTM — R9-EXACT revert (890 us PASS version) ----------------
// Spin-on-data: h(t) published as ONE 8B relaxed agent atomic (tag|payload);
// 384 staging threads poll; dots by 768 threads; gate math CENTRALIZED in
// wave 0 (24 threads) -> 24 contiguous tagged stores in one burst (locality
// of publish is what R10 broke). Two barriers/step make single-buffer hsm safe.
#define NWG 16
#define CPW 24
__global__ __launch_bounds__(768) void lstm_k(
    const float* __restrict__ gin, const float* __restrict__ whh,
    float* __restrict__ out, unsigned long long* __restrict__ tagged)
{
  __shared__ __align__(16) float hsm[8][52];
  __shared__ float gsum[96];
  const int wg = blockIdx.x, tid = threadIdx.x;
  const int r = tid >> 3, lk = tid & 7;
  const int gq = r / CPW, cl = r % CPW;
  const int grow = gq * 384 + wg * CPW + cl;
  float wreg[48];
  {
    const float* wr = whh + (size_t)grow * 384 + lk * 48;
#pragma unroll
    for (int i = 0; i < 48; ++i) wreg[i] = wr[i];
  }
  float c = 0.f;
  __syncthreads();
  for (int t = 0; t < 512; ++t) {
    float g0 = 0.f, g1 = 0.f, g2 = 0.f, g3 = 0.f;
    if (tid < CPW) {
      const int j = wg * CPW + tid;
      g0 = gin[(size_t)t * 1536 + 0 * 384 + j];
      g1 = gin[(size_t)t * 1536 + 1 * 384 + j];
      g2 = gin[(size_t)t * 1536 + 2 * 384 + j];
      g3 = gin[(size_t)t * 1536 + 3 * 384 + j];
    }
    if (tid < 384) {
      float hv;
      if (t == 0) {
        hv = 0.f;
      } else {
        unsigned long long u;
        do {
          u = __hip_atomic_load(&tagged[(size_t)(t - 1) * 384 + tid],
                                __ATOMIC_RELAXED, __HIP_MEMORY_SCOPE_AGENT);
        } while ((unsigned)(u >> 32) != (unsigned)t);
        union { unsigned ui; float f; } cv; cv.ui = (unsigned)u; hv = cv.f;
      }
      hsm[tid / 48][tid % 48] = hv;
    }
    __syncthreads();
    float s = 0.f;
    {
      const float4* hp = (const float4*)&hsm[lk][0];
#pragma unroll
      for (int q = 0; q < 12; ++q) {
        const float4 hv = hp[q];
        s += wreg[4 * q + 0] * hv.x + wreg[4 * q + 1] * hv.y
           + wreg[4 * q + 2] * hv.z + wreg[4 * q + 3] * hv.w;
      }
    }
    s += __shfl_xor(s, 1);
    s += __shfl_xor(s, 2);
    s += __shfl_xor(s, 4);
    if (lk == 0) gsum[r] = s;
    __syncthreads();
    if (tid < CPW) {
      const float gi = gsum[0 * CPW + tid] + g0;
      const float gf = gsum[1 * CPW + tid] + g1;
      const float gg = gsum[2 * CPW + tid] + g2;
      const float go = gsum[3 * CPW + tid] + g3;
      const float si = 1.f / (1.f + expf(-gi));
      const float sf = 1.f / (1.f + expf(-gf));
      const float so = 1.f / (1.f + expf(-go));
      c = sf * c + si * tanhf(gg);
      const float hn = so * tanhf(c);
      const int j = wg * CPW + tid;
      union { float f; unsigned ui; } cv; cv.f = hn;
      const unsigned long long pk = ((unsigned long long)(t + 1) << 32) | cv.ui;
      __hip_atomic_store(&tagged[(size_t)t * 384 + j], pk,
                         __ATOMIC_RELAXED, __HIP_MEMORY_SCOPE_AGENT);
      out[(size_t)t * 384 + j] = hn;
    }
    // no end-of-step barrier: staging(t+1) gated by the post-dot barrier above
  }
}

extern "C" void kernel_launch(void* const* d_in, const int* in_sizes, int n_in,
                              void* d_out, int out_size, void* d_ws, size_t ws_size,
                              hipStream_t stream)
{
  const float* x   = (const float*)d_in[0];
  const float* cw1 = (const float*)d_in[1];
  const float* cb1 = (const float*)d_in[2];
  const float* cw2 = (const float*)d_in[3];
  const float* cb2 = (const float*)d_in[4];
  const float* cw3 = (const float*)d_in[5];
  const float* cb3 = (const float*)d_in[6];
  const float* cw4 = (const float*)d_in[7];
  const float* cb4 = (const float*)d_in[8];
  const float* cw5 = (const float*)d_in[9];
  const float* cb5 = (const float*)d_in[10];
  const float* cw6 = (const float*)d_in[11];
  const float* cb6 = (const float*)d_in[12];
  const float* lw1 = (const float*)d_in[13];
  const float* lb1 = (const float*)d_in[14];
  const float* lw2 = (const float*)d_in[15];
  const float* lb2 = (const float*)d_in[16];
  const float* wih = (const float*)d_in[17];
  const float* whh = (const float*)d_in[18];
  const float* bih = (const float*)d_in[19];
  const float* bhh = (const float*)d_in[20];
  float* out = (float*)d_out;
  char* ws = (char*)d_ws;

  // workspace layout (R3-fixed, proven)
  float* bufA = (float*)(ws);                       // 72.4 MB conv ping
  float* bufB = (float*)(ws + 72384512);            // 51.4 MB conv pong
  float* l1o  = (float*)(ws + 123764736);           // 2 MB
  float* x2   = (float*)(ws + 125861888);
  float* gin  = (float*)(ws + 126648320);
  // conv bswz weights in l1o region (dead until linear1 output overwrites):
  ushort* bw3 = (ushort*)(ws + 123764736);
  ushort* bw4 = (ushort*)(ws + 123764736 + 102400);
  ushort* bw5 = (ushort*)(ws + 123764736 + 512000);
  ushort* bw6 = (ushort*)(ws + 123764736 + 1331200);
  ushort* bw2 = (ushort*)(ws + 123764736 + 1626112);
  // post-conv6 scratch inside then-dead bufA region:
  ushort* bw1 = (ushort*)(ws);                      // 16.8 MB swizzled lw1 bf16
  ushort* abf = (ushort*)(ws + 16777216);           // 8.4 MB conv6-out bf16
  unsigned long long* tagged = (unsigned long long*)(ws + 25165824);  // 1.57 MB

  // conv weight pre-swizzles (l1o region free until linear1)
  wprep_k<<<(25 * 4 * 64 + 255) / 256, 256, 0, stream>>>(cw3, bw3, 32, 5, 64, 25 * 4 * 64);
  wprep_k<<<(50 * 8 * 64 + 255) / 256, 256, 0, stream>>>(cw4, bw4, 64, 5, 128, 50 * 8 * 64);
  wprep_k<<<(100 * 8 * 64 + 255) / 256, 256, 0, stream>>>(cw5, bw5, 128, 5, 128, 100 * 8 * 64);
  wprep_k<<<(36 * 8 * 64 + 255) / 256, 256, 0, stream>>>(cw6, bw6, 128, 3, 128, 36 * 8 * 64);
  wprep_k<<<(8 * 2 * 64 + 255) / 256, 256, 0, stream>>>(cw2, bw2, 16, 4, 32, 8 * 2 * 64);

  conv1_pool_k<<<512, 256, 0, stream>>>(x, cw1, cb1, bufA);
  conv2mfma_k<<<512, 256, 0, stream>>>(bufA, bw2, cb2, bufB);
  convmfma_k<32, 22, 22, 5, 64, 7><<<512, 256, 0, stream>>>(bufB, bw3, cb3, bufA);
  convmfma_k<64, 18, 18, 5, 128, 7><<<512, 256, 0, stream>>>(bufA, bw4, cb4, bufB);
  convmfma_k<128, 14, 14, 5, 128, 7><<<512, 256, 0, stream>>>(bufB, bw5, cb5, bufA);
  convmfma_k<128, 10, 10, 3, 128, 4><<<512, 256, 0, stream>>>(bufA, bw6, cb6, bufB);
  // bufA now dead -> linear1 scratch + tagged live there
  wprep_lin_k<<<(256 * 64 * 64 + 255) / 256, 256, 0, stream>>>(lw1, bw1, 8192, 64, 256 * 64 * 64);
  f2bf_k<<<(512 * 8192 / 4 + 255) / 256, 256, 0, stream>>>(bufB, abf, 512 * 8192);
  hipMemsetAsync(tagged, 0, 512 * 384 * 8, stream);
  gemm_bf16_k<<<dim3(16, 8), 256, 0, stream>>>(abf, bw1, lb1, l1o, 512, 1024, 8192);
  gemm_tn_k<1><<<dim3(384 / 32, 512 / 64), 256, 0, stream>>>(l1o, lw2, lb2, nullptr, x2, 512, 384, 1024);
  gemm_tn_k<0><<<dim3(1536 / 32, 512 / 64), 256, 0, stream>>>(x2, wih, bih, bhh, gin, 512, 1536, 384);
  lstm_k<<<NWG, 768, 0, stream>>>(gin, whh, out, tagged);
}

// Round 12
// 1428.048 us; speedup vs baseline: 1.3780x; 1.0577x over previous
//
#include <hip/hip_runtime.h>
#include <cstddef>
#include <cstdint>

#define T256 256

typedef __attribute__((ext_vector_type(8))) short bhalf8;
typedef __attribute__((ext_vector_type(4))) float floatx4;

__device__ __forceinline__ ushort f2bf(float f) {
  union { float f; uint32_t u; } v; v.f = f;
  return (ushort)((v.u + 0x7fffu + ((v.u >> 16) & 1u)) >> 16);
}

// fast gate activations: v_exp_f32-based, overflow-safe
__device__ __forceinline__ float fsig(float x) {
  return 1.f / (1.f + __expf(-x));
}
__device__ __forceinline__ float ftanh(float x) {
  const float e = __expf(-2.f * fabsf(x));
  const float r = (1.f - e) / (1.f + e);
  return copysignf(r, x);
}

// ---------------- conv1 (1->16, 7x7, relu, maxpool2) — unchanged R11 PASS ----------------
__global__ __launch_bounds__(256) void conv1_pool_k(
    const float* __restrict__ x, const float* __restrict__ w,
    const float* __restrict__ bias, float* __restrict__ out)
{
  __shared__ float img[10000];
  __shared__ float wsm[16 * 49];
  __shared__ float bsm[16];
  const int b = blockIdx.x, tid = threadIdx.x;
  for (int i = tid; i < 10000; i += T256) img[i] = x[(size_t)b * 10000 + i];
  for (int i = tid; i < 16 * 49; i += T256) wsm[i] = w[i];
  if (tid < 16) bsm[tid] = bias[tid];
  __syncthreads();
  for (int p = tid; p < 47 * 47; p += T256) {
    const int py = p / 47, px = p % 47;
    const int iy0 = 2 * py, ix0 = 2 * px;
    float win[8][8];
#pragma unroll
    for (int r = 0; r < 8; ++r)
#pragma unroll
      for (int c = 0; c < 8; ++c)
        win[r][c] = img[(iy0 + r) * 100 + (ix0 + c)];
#pragma unroll 1
    for (int oc = 0; oc < 16; ++oc) {
      float wr[49];
#pragma unroll
      for (int j = 0; j < 49; ++j) wr[j] = wsm[oc * 49 + j];
      float m = 0.f;
#pragma unroll
      for (int dy = 0; dy < 2; ++dy)
#pragma unroll
        for (int dx = 0; dx < 2; ++dx) {
          float s = bsm[oc];
#pragma unroll
          for (int ky = 0; ky < 7; ++ky)
#pragma unroll
            for (int kx = 0; kx < 7; ++kx)
              s += win[dy + ky][dx + kx] * wr[ky * 7 + kx];
          m = fmaxf(m, s);
        }
      out[((size_t)b * 16 + oc) * 2209 + p] = m;
    }
  }
}

// ---------------- fused weight pre-swizzle (all 5 MFMA convs, 1 launch) ----------------
__device__ __forceinline__ void wprep_one(
    const float* __restrict__ w, ushort* __restrict__ bswz,
    int IC, int KW, int OC, int idx)
{
  const int NT = OC / 16;
  const int lane = idx & 63;
  const int nt = (idx >> 6) % NT;
  const int ks = idx / (64 * NT);
  const int oc = nt * 16 + (lane & 15);
  const int kb = ks * 32 + (lane >> 4) * 8;
  ushort tmp[8];
#pragma unroll
  for (int j = 0; j < 8; ++j) {
    const int k = kb + j;
    const int ic = k % IC, tap = k / IC;
    tmp[j] = f2bf(w[((size_t)oc * IC + ic) * (KW * KW) + tap]);
  }
  *(bhalf8*)(bswz + (size_t)idx * 8) = *(const bhalf8*)tmp;
}

__global__ __launch_bounds__(256) void wprep_all_k(
    const float* __restrict__ cw2, const float* __restrict__ cw3,
    const float* __restrict__ cw4, const float* __restrict__ cw5,
    const float* __restrict__ cw6,
    ushort* __restrict__ bw2, ushort* __restrict__ bw3,
    ushort* __restrict__ bw4, ushort* __restrict__ bw5,
    ushort* __restrict__ bw6)
{
  int idx = blockIdx.x * 256 + threadIdx.x;
  if (idx < 6400)  { wprep_one(cw3, bw3, 32, 5, 64, idx); return; }
  idx -= 6400;
  if (idx < 25600) { wprep_one(cw4, bw4, 64, 5, 128, idx); return; }
  idx -= 25600;
  if (idx < 51200) { wprep_one(cw5, bw5, 128, 5, 128, idx); return; }
  idx -= 51200;
  if (idx < 18432) { wprep_one(cw6, bw6, 128, 3, 128, idx); return; }
  idx -= 18432;
  if (idx < 1024)  { wprep_one(cw2, bw2, 16, 4, 32, idx); }
}

// ---------------- linear-weight pre-swizzle ----------------
__global__ __launch_bounds__(256) void wprep_lin_k(
    const float* __restrict__ w, ushort* __restrict__ bswz,
    int Kdim, int NT, int total)
{
  const int idx = blockIdx.x * 256 + threadIdx.x;
  if (idx >= total) return;
  const int lane = idx & 63;
  const int nt = (idx >> 6) % NT;
  const int ks = idx / (64 * NT);
  const int oc = nt * 16 + (lane & 15);
  const int kb = ks * 32 + (lane >> 4) * 8;
  ushort tmp[8];
#pragma unroll
  for (int j = 0; j < 8; ++j) tmp[j] = f2bf(w[(size_t)oc * Kdim + kb + j]);
  *(bhalf8*)(bswz + (size_t)idx * 8) = *(const bhalf8*)tmp;
}

// ---------------- f32 -> bf16 convert ----------------
__global__ __launch_bounds__(256) void f2bf_k(
    const float* __restrict__ in, ushort* __restrict__ outv, int n)
{
  const int i = (blockIdx.x * 256 + threadIdx.x) * 4;
  if (i >= n) return;
  const float4 v = *(const float4*)&in[i];
  ushort tmp[4] = {f2bf(v.x), f2bf(v.y), f2bf(v.z), f2bf(v.w)};
  *(uint2*)&outv[i] = *(const uint2*)tmp;
}

// ---------------- conv2 MFMA with in-register 2x2 maxpool — unchanged PASS ----------------
__global__ __launch_bounds__(256) void conv2mfma_k(
    const float* __restrict__ in, const ushort* __restrict__ bswz,
    const float* __restrict__ bias, float* __restrict__ out)
{
  constexpr int IC = 16, IH = 47, IW = 47;
  constexpr int NPIX = IH * IW;
  constexpr int ROWU = IC + 8;
  constexpr int KS = 8;
  __shared__ ushort imgT[NPIX * ROWU];
  const int b = blockIdx.x, tid = threadIdx.x;
  const int lane = tid & 63, wv = tid >> 6;

  for (int e = tid; e < IC * NPIX; e += 256) {
    const int ic = e / NPIX, pix = e % NPIX;
    imgT[pix * ROWU + ic] = f2bf(in[((size_t)b * IC + ic) * NPIX + pix]);
  }
  __syncthreads();

  const int col = lane & 15, g = lane >> 4;
  const float b0 = bias[col], b1 = bias[16 + col];

  for (int it = wv; it < 66; it += 4) {
    const int pyp = it / 3, tx = it - pyp * 3;
    int px = tx * 16 + col; px = px < 43 ? px : 43;
    floatx4 acc[2][2];
#pragma unroll
    for (int dy = 0; dy < 2; ++dy)
#pragma unroll
      for (int nt = 0; nt < 2; ++nt) acc[dy][nt] = (floatx4){0.f, 0.f, 0.f, 0.f};

    for (int ks = 0; ks < KS; ++ks) {
      bhalf8 bf[2];
#pragma unroll
      for (int nt = 0; nt < 2; ++nt)
        bf[nt] = *(const bhalf8*)(bswz + ((size_t)(ks * 2 + nt) * 64 + lane) * 8);
      const int kk = ks * 32 + g * 8;
      const int tap = kk >> 4, icb = kk & 15;
      const int ky = tap >> 2, kx = tap & 3;
      bhalf8 af[2];
#pragma unroll
      for (int dy = 0; dy < 2; ++dy)
        af[dy] = *(const bhalf8*)&imgT[((2 * pyp + dy + ky) * IW + px + kx) * ROWU + icb];
#pragma unroll
      for (int dy = 0; dy < 2; ++dy)
#pragma unroll
        for (int nt = 0; nt < 2; ++nt)
          acc[dy][nt] = __builtin_amdgcn_mfma_f32_16x16x32_bf16(
              af[dy], bf[nt], acc[dy][nt], 0, 0, 0);
    }
#pragma unroll
    for (int nt = 0; nt < 2; ++nt) {
      const int oc = nt * 16 + col;
      const float bb = nt ? b1 : b0;
      float vv[4];
#pragma unroll
      for (int i = 0; i < 4; ++i) vv[i] = fmaxf(acc[0][nt][i], acc[1][nt][i]);
#pragma unroll
      for (int q = 0; q < 2; ++q) {
        const int pxp = tx * 8 + g * 2 + q;
        if (pxp < 22) {
          const float v = fmaxf(fmaxf(vv[2 * q], vv[2 * q + 1]) + bb, 0.f);
          out[((size_t)b * 32 + oc) * 484 + pyp * 22 + pxp] = v;
        }
      }
    }
  }
}

// ---------------- MFMA implicit-GEMM conv (+bias+relu) — unchanged PASS ----------------
template <int IC, int IH, int IW, int KW_, int OC, int MC>
__global__ __launch_bounds__(256) void convmfma_k(
    const float* __restrict__ in, const ushort* __restrict__ bswz,
    const float* __restrict__ bias, float* __restrict__ out)
{
  constexpr int OH = IH - KW_ + 1, OW = IW - KW_ + 1, P = OH * OW;
  constexpr int NPIX = IH * IW;
  constexpr int KS = IC * KW_ * KW_ / 32;
  constexpr int NT = OC / 16;
  constexpr int NPW = NT / 4;
  constexpr int MT = (P + 15) / 16;
  constexpr int ROWU = IC + 8;
  static_assert(NT % 4 == 0 && IC % 32 == 0, "cfg");

  __shared__ ushort imgT[NPIX * ROWU];
  const int b = blockIdx.x, tid = threadIdx.x;
  const int lane = tid & 63, wv = tid >> 6;
  const int icoff = (lane >> 4) * 8;

  for (int e = tid; e < IC * NPIX; e += 256) {
    const int ic = e / NPIX, pix = e % NPIX;
    imgT[pix * ROWU + ic] = f2bf(in[((size_t)b * IC + ic) * NPIX + pix]);
  }
  __syncthreads();

  for (int m0 = 0; m0 < MT; m0 += MC) {
    floatx4 acc[MC][NPW];
#pragma unroll
    for (int mi = 0; mi < MC; ++mi)
#pragma unroll
      for (int nn = 0; nn < NPW; ++nn)
        acc[mi][nn] = (floatx4){0.f, 0.f, 0.f, 0.f};

    int pbase[MC];
#pragma unroll
    for (int mi = 0; mi < MC; ++mi) {
      int p = (m0 + mi) * 16 + (lane & 15);
      p = p < P ? p : P - 1;
      pbase[mi] = ((p / OW) * IW + (p % OW)) * ROWU;
    }

    bhalf8 bcur[NPW];
#pragma unroll
    for (int nn = 0; nn < NPW; ++nn)
      bcur[nn] = *(const bhalf8*)(bswz + ((size_t)(wv * NPW + nn) * 64 + lane) * 8);

    for (int ks = 0; ks < KS; ++ks) {
      bhalf8 bnext[NPW];
      if (ks + 1 < KS) {
#pragma unroll
        for (int nn = 0; nn < NPW; ++nn)
          bnext[nn] = *(const bhalf8*)(bswz +
              ((size_t)((ks + 1) * NT + wv * NPW + nn) * 64 + lane) * 8);
      }
      const int tap = (ks * 32) / IC;
      const int icb = (ks * 32) % IC;
      const int aoff = ((tap / KW_) * IW + (tap % KW_)) * ROWU + icb + icoff;
      bhalf8 af[MC];
#pragma unroll
      for (int mi = 0; mi < MC; ++mi)
        af[mi] = *(const bhalf8*)&imgT[pbase[mi] + aoff];
#pragma unroll
      for (int mi = 0; mi < MC; ++mi)
#pragma unroll
        for (int nn = 0; nn < NPW; ++nn)
          acc[mi][nn] = __builtin_amdgcn_mfma_f32_16x16x32_bf16(
              af[mi], bcur[nn], acc[mi][nn], 0, 0, 0);
      if (ks + 1 < KS) {
#pragma unroll
        for (int nn = 0; nn < NPW; ++nn) bcur[nn] = bnext[nn];
      }
    }
#pragma unroll
    for (int mi = 0; mi < MC; ++mi)
#pragma unroll
      for (int nn = 0; nn < NPW; ++nn) {
        const int oc = (wv * NPW + nn) * 16 + (lane & 15);
#pragma unroll
        for (int i = 0; i < 4; ++i) {
          const int p = (m0 + mi) * 16 + (lane >> 4) * 4 + i;
          if (p < P) {
            const float v = fmaxf(acc[mi][nn][i] + bias[oc], 0.f);
            out[((size_t)b * OC + oc) * P + p] = v;
          }
        }
      }
  }
}

// ---------------- bf16 MFMA GEMM (linear1) — unchanged PASS ----------------
__global__ __launch_bounds__(256) void gemm_bf16_k(
    const ushort* __restrict__ abf, const ushort* __restrict__ bswz,
    const float* __restrict__ bias, float* __restrict__ C,
    int M, int N, int K)
{
  __shared__ ushort As[64][72];
  const int bn = blockIdx.x, bm = blockIdx.y, tid = threadIdx.x;
  const int lane = tid & 63, wv = tid >> 6;
  const int m0 = bm * 64, n0 = bn * 64;
  const int NTg = N / 16;
  const int ntg = bn * 4 + wv;
  floatx4 acc[4];
#pragma unroll
  for (int mt = 0; mt < 4; ++mt) acc[mt] = (floatx4){0.f, 0.f, 0.f, 0.f};

  for (int kc = 0; kc < K / 64; ++kc) {
    __syncthreads();
#pragma unroll
    for (int q = 0; q < 2; ++q) {
      const int id = q * 256 + tid;
      const int row = id >> 3, kcol = (id & 7) * 8;
      *(bhalf8*)&As[row][kcol] =
          *(const bhalf8*)&abf[(size_t)(m0 + row) * K + kc * 64 + kcol];
    }
    __syncthreads();
#pragma unroll
    for (int k2 = 0; k2 < 2; ++k2) {
      const int ks = kc * 2 + k2;
      const bhalf8 bf = *(const bhalf8*)(bswz + ((size_t)(ks * NTg + ntg) * 64 + lane) * 8);
      const int ksub = k2 * 32 + (lane >> 4) * 8;
#pragma unroll
      for (int mt = 0; mt < 4; ++mt) {
        const bhalf8 af = *(const bhalf8*)&As[mt * 16 + (lane & 15)][ksub];
        acc[mt] = __builtin_amdgcn_mfma_f32_16x16x32_bf16(af, bf, acc[mt], 0, 0, 0);
      }
    }
  }
  const int n = n0 + wv * 16 + (lane & 15);
  const float bb = bias[n];
#pragma unroll
  for (int mt = 0; mt < 4; ++mt)
#pragma unroll
    for (int i = 0; i < 4; ++i) {
      const int m = m0 + mt * 16 + (lane >> 4) * 4 + i;
      C[(size_t)m * N + n] = acc[mt][i] + bb;
    }
}

// ---------------- fp32 tiled GEMM (linear2, gin) — unchanged PASS ----------------
template <int ACT>
__global__ __launch_bounds__(256) void gemm_tn_k(
    const float* __restrict__ A, const float* __restrict__ B,
    const float* __restrict__ b1, const float* __restrict__ b2,
    float* __restrict__ C, int M, int N, int K)
{
  __shared__ float As[32][66];
  __shared__ float Bs[32][36];
  const int bn = blockIdx.x, bm = blockIdx.y, tid = threadIdx.x;
  const int tx = tid & 7, ty = tid >> 3;
  const int m0 = bm * 64, n0 = bn * 32;
  double acc[2][4] = {{0, 0, 0, 0}, {0, 0, 0, 0}};
  for (int k0 = 0; k0 < K; k0 += 32) {
    __syncthreads();
#pragma unroll
    for (int l = 0; l < 8; ++l) {
      int id = tid + l * 256;
      int kk = id & 31, mm = id >> 5;
      As[kk][mm] = A[(size_t)(m0 + mm) * K + (k0 + kk)];
    }
#pragma unroll
    for (int l = 0; l < 4; ++l) {
      int id = tid + l * 256;
      int kk = id & 31, nn = id >> 5;
      Bs[kk][nn] = B[(size_t)(n0 + nn) * K + (k0 + kk)];
    }
    __syncthreads();
    float p[2][4] = {{0.f, 0.f, 0.f, 0.f}, {0.f, 0.f, 0.f, 0.f}};
#pragma unroll
    for (int kk = 0; kk < 32; ++kk) {
      const float2 av = *reinterpret_cast<const float2*>(&As[kk][ty * 2]);
      const float4 bv = *reinterpret_cast<const float4*>(&Bs[kk][tx * 4]);
      p[0][0] += av.x * bv.x; p[0][1] += av.x * bv.y;
      p[0][2] += av.x * bv.z; p[0][3] += av.x * bv.w;
      p[1][0] += av.y * bv.x; p[1][1] += av.y * bv.y;
      p[1][2] += av.y * bv.z; p[1][3] += av.y * bv.w;
    }
#pragma unroll
    for (int i = 0; i < 2; ++i)
#pragma unroll
      for (int j = 0; j < 4; ++j) acc[i][j] += (double)p[i][j];
  }
#pragma unroll
  for (int i = 0; i < 2; ++i) {
    const int m = m0 + ty * 2 + i;
#pragma unroll
    for (int j = 0; j < 4; ++j) {
      const int n = n0 + tx * 4 + j;
      double v = acc[i][j] + (double)b1[n];
      if (b2) v += (double)b2[n];
      if (ACT == 1) v = 1.0 / (1.0 + exp(-v));
      C[(size_t)m * N + n] = (float)v;
    }
  }
}

// ---------------- persistent LSTM — R9 protocol + fast gates + wave0 prio ----------------
// Spin-on-data (proven): h(t) = ONE 8B relaxed agent atomic (tag|payload);
// gate math CENTRALIZED in wave 0 (burst publish). R12: __expf-based
// sigmoid/tanh (hw v_exp_f32) shortens the wave0 critical section; wave0
// runs at s_setprio(1) so its gates phase wins issue slots vs polling waves.
#define NWG 16
#define CPW 24
__global__ __launch_bounds__(768) void lstm_k(
    const float* __restrict__ gin, const float* __restrict__ whh,
    float* __restrict__ out, unsigned long long* __restrict__ tagged)
{
  __shared__ __align__(16) float hsm[8][52];
  __shared__ float gsum[96];
  const int wg = blockIdx.x, tid = threadIdx.x;
  const int r = tid >> 3, lk = tid & 7;
  const int gq = r / CPW, cl = r % CPW;
  const int grow = gq * 384 + wg * CPW + cl;
  float wreg[48];
  {
    const float* wr = whh + (size_t)grow * 384 + lk * 48;
#pragma unroll
    for (int i = 0; i < 48; ++i) wreg[i] = wr[i];
  }
  float c = 0.f;
  if (tid < 64) __builtin_amdgcn_s_setprio(1);  // wave0 = critical producer
  __syncthreads();
  for (int t = 0; t < 512; ++t) {
    float g0 = 0.f, g1 = 0.f, g2 = 0.f, g3 = 0.f;
    if (tid < CPW) {
      const int j = wg * CPW + tid;
      g0 = gin[(size_t)t * 1536 + 0 * 384 + j];
      g1 = gin[(size_t)t * 1536 + 1 * 384 + j];
      g2 = gin[(size_t)t * 1536 + 2 * 384 + j];
      g3 = gin[(size_t)t * 1536 + 3 * 384 + j];
    }
    if (tid < 384) {
      float hv;
      if (t == 0) {
        hv = 0.f;
      } else {
        unsigned long long u;
        do {
          u = __hip_atomic_load(&tagged[(size_t)(t - 1) * 384 + tid],
                                __ATOMIC_RELAXED, __HIP_MEMORY_SCOPE_AGENT);
        } while ((unsigned)(u >> 32) != (unsigned)t);
        union { unsigned ui; float f; } cv; cv.ui = (unsigned)u; hv = cv.f;
      }
      hsm[tid / 48][tid % 48] = hv;
    }
    __syncthreads();
    float s = 0.f;
    {
      const float4* hp = (const float4*)&hsm[lk][0];
#pragma unroll
      for (int q = 0; q < 12; ++q) {
        const float4 hv = hp[q];
        s += wreg[4 * q + 0] * hv.x + wreg[4 * q + 1] * hv.y
           + wreg[4 * q + 2] * hv.z + wreg[4 * q + 3] * hv.w;
      }
    }
    s += __shfl_xor(s, 1);
    s += __shfl_xor(s, 2);
    s += __shfl_xor(s, 4);
    if (lk == 0) gsum[r] = s;
    __syncthreads();
    if (tid < CPW) {
      const float gi = gsum[0 * CPW + tid] + g0;
      const float gf = gsum[1 * CPW + tid] + g1;
      const float gg = gsum[2 * CPW + tid] + g2;
      const float go = gsum[3 * CPW + tid] + g3;
      const float si = fsig(gi);
      const float sf = fsig(gf);
      const float so = fsig(go);
      c = sf * c + si * ftanh(gg);
      const float hn = so * ftanh(c);
      const int j = wg * CPW + tid;
      union { float f; unsigned ui; } cv; cv.f = hn;
      const unsigned long long pk = ((unsigned long long)(t + 1) << 32) | cv.ui;
      __hip_atomic_store(&tagged[(size_t)t * 384 + j], pk,
                         __ATOMIC_RELAXED, __HIP_MEMORY_SCOPE_AGENT);
      out[(size_t)t * 384 + j] = hn;
    }
    // no end-of-step barrier: staging(t+1) gated by the post-dot barrier above
  }
}

extern "C" void kernel_launch(void* const* d_in, const int* in_sizes, int n_in,
                              void* d_out, int out_size, void* d_ws, size_t ws_size,
                              hipStream_t stream)
{
  const float* x   = (const float*)d_in[0];
  const float* cw1 = (const float*)d_in[1];
  const float* cb1 = (const float*)d_in[2];
  const float* cw2 = (const float*)d_in[3];
  const float* cb2 = (const float*)d_in[4];
  const float* cw3 = (const float*)d_in[5];
  const float* cb3 = (const float*)d_in[6];
  const float* cw4 = (const float*)d_in[7];
  const float* cb4 = (const float*)d_in[8];
  const float* cw5 = (const float*)d_in[9];
  const float* cb5 = (const float*)d_in[10];
  const float* cw6 = (const float*)d_in[11];
  const float* cb6 = (const float*)d_in[12];
  const float* lw1 = (const float*)d_in[13];
  const float* lb1 = (const float*)d_in[14];
  const float* lw2 = (const float*)d_in[15];
  const float* lb2 = (const float*)d_in[16];
  const float* wih = (const float*)d_in[17];
  const float* whh = (const float*)d_in[18];
  const float* bih = (const float*)d_in[19];
  const float* bhh = (const float*)d_in[20];
  float* out = (float*)d_out;
  char* ws = (char*)d_ws;

  // workspace layout (R3-fixed, proven)
  float* bufA = (float*)(ws);                       // 72.4 MB conv ping
  float* bufB = (float*)(ws + 72384512);            // 51.4 MB conv pong
  float* l1o  = (float*)(ws + 123764736);           // 2 MB
  float* x2   = (float*)(ws + 125861888);
  float* gin  = (float*)(ws + 126648320);
  // conv bswz weights in l1o region (dead until linear1 output overwrites):
  ushort* bw3 = (ushort*)(ws + 123764736);
  ushort* bw4 = (ushort*)(ws + 123764736 + 102400);
  ushort* bw5 = (ushort*)(ws + 123764736 + 512000);
  ushort* bw6 = (ushort*)(ws + 123764736 + 1331200);
  ushort* bw2 = (ushort*)(ws + 123764736 + 1626112);
  // post-conv6 scratch inside then-dead bufA region:
  ushort* bw1 = (ushort*)(ws);                      // 16.8 MB swizzled lw1 bf16
  ushort* abf = (ushort*)(ws + 16777216);           // 8.4 MB conv6-out bf16
  unsigned long long* tagged = (unsigned long long*)(ws + 25165824);  // 1.57 MB

  // fused conv weight pre-swizzle: 6400+25600+51200+18432+1024 = 102656 items
  wprep_all_k<<<(102656 + 255) / 256, 256, 0, stream>>>(
      cw2, cw3, cw4, cw5, cw6, bw2, bw3, bw4, bw5, bw6);

  conv1_pool_k<<<512, 256, 0, stream>>>(x, cw1, cb1, bufA);
  conv2mfma_k<<<512, 256, 0, stream>>>(bufA, bw2, cb2, bufB);
  convmfma_k<32, 22, 22, 5, 64, 7><<<512, 256, 0, stream>>>(bufB, bw3, cb3, bufA);
  convmfma_k<64, 18, 18, 5, 128, 7><<<512, 256, 0, stream>>>(bufA, bw4, cb4, bufB);
  convmfma_k<128, 14, 14, 5, 128, 7><<<512, 256, 0, stream>>>(bufB, bw5, cb5, bufA);
  convmfma_k<128, 10, 10, 3, 128, 4><<<512, 256, 0, stream>>>(bufA, bw6, cb6, bufB);
  // bufA now dead -> linear1 scratch + tagged live there
  wprep_lin_k<<<(256 * 64 * 64 + 255) / 256, 256, 0, stream>>>(lw1, bw1, 8192, 64, 256 * 64 * 64);
  f2bf_k<<<(512 * 8192 / 4 + 255) / 256, 256, 0, stream>>>(bufB, abf, 512 * 8192);
  hipMemsetAsync(tagged, 0, 512 * 384 * 8, stream);
  gemm_bf16_k<<<dim3(16, 8), 256, 0, stream>>>(abf, bw1, lb1, l1o, 512, 1024, 8192);
  gemm_tn_k<1><<<dim3(384 / 32, 512 / 64), 256, 0, stream>>>(l1o, lw2, lb2, nullptr, x2, 512, 384, 1024);
  gemm_tn_k<0><<<dim3(1536 / 32, 512 / 64), 256, 0, stream>>>(x2, wih, bih, bhh, gin, 512, 1536, 384);
  lstm_k<<<NWG, 768, 0, stream>>>(gin, whh, out, tagged);
}

// Round 15
// 1421.266 us; speedup vs baseline: 1.3846x; 1.0048x over previous
//
#include <hip/hip_runtime.h>
#include <cstddef>
#include <cstdint>

#define T256 256

typedef __attribute__((ext_vector_type(8))) short bhalf8;
typedef __attribute__((ext_vector_type(4))) float floatx4;

__device__ __forceinline__ ushort f2bf(float f) {
  union { float f; uint32_t u; } v; v.f = f;
  return (ushort)((v.u + 0x7fffu + ((v.u >> 16) & 1u)) >> 16);
}

// fast gate activations: v_exp_f32-based, overflow-safe
__device__ __forceinline__ float fsig(float x) {
  return 1.f / (1.f + __expf(-x));
}
__device__ __forceinline__ float ftanh(float x) {
  const float e = __expf(-2.f * fabsf(x));
  const float r = (1.f - e) / (1.f + e);
  return copysignf(r, x);
}

// ---------------- conv1 (1->16, 7x7, relu, maxpool2) — unchanged PASS ----------------
__global__ __launch_bounds__(256) void conv1_pool_k(
    const float* __restrict__ x, const float* __restrict__ w,
    const float* __restrict__ bias, float* __restrict__ out)
{
  __shared__ float img[10000];
  __shared__ float wsm[16 * 49];
  __shared__ float bsm[16];
  const int b = blockIdx.x, tid = threadIdx.x;
  for (int i = tid; i < 10000; i += T256) img[i] = x[(size_t)b * 10000 + i];
  for (int i = tid; i < 16 * 49; i += T256) wsm[i] = w[i];
  if (tid < 16) bsm[tid] = bias[tid];
  __syncthreads();
  for (int p = tid; p < 47 * 47; p += T256) {
    const int py = p / 47, px = p % 47;
    const int iy0 = 2 * py, ix0 = 2 * px;
    float win[8][8];
#pragma unroll
    for (int r = 0; r < 8; ++r)
#pragma unroll
      for (int c = 0; c < 8; ++c)
        win[r][c] = img[(iy0 + r) * 100 + (ix0 + c)];
#pragma unroll 1
    for (int oc = 0; oc < 16; ++oc) {
      float wr[49];
#pragma unroll
      for (int j = 0; j < 49; ++j) wr[j] = wsm[oc * 49 + j];
      float m = 0.f;
#pragma unroll
      for (int dy = 0; dy < 2; ++dy)
#pragma unroll
        for (int dx = 0; dx < 2; ++dx) {
          float s = bsm[oc];
#pragma unroll
          for (int ky = 0; ky < 7; ++ky)
#pragma unroll
            for (int kx = 0; kx < 7; ++kx)
              s += win[dy + ky][dx + kx] * wr[ky * 7 + kx];
          m = fmaxf(m, s);
        }
      out[((size_t)b * 16 + oc) * 2209 + p] = m;
    }
  }
}

// ---------------- fused conv weight pre-swizzle (proven) ----------------
__device__ __forceinline__ void wprep_one(
    const float* __restrict__ w, ushort* __restrict__ bswz,
    int IC, int KW, int OC, int idx)
{
  const int NT = OC / 16;
  const int lane = idx & 63;
  const int nt = (idx >> 6) % NT;
  const int ks = idx / (64 * NT);
  const int oc = nt * 16 + (lane & 15);
  const int kb = ks * 32 + (lane >> 4) * 8;
  ushort tmp[8];
#pragma unroll
  for (int j = 0; j < 8; ++j) {
    const int k = kb + j;
    const int ic = k % IC, tap = k / IC;
    tmp[j] = f2bf(w[((size_t)oc * IC + ic) * (KW * KW) + tap]);
  }
  *(bhalf8*)(bswz + (size_t)idx * 8) = *(const bhalf8*)tmp;
}

__global__ __launch_bounds__(256) void wprep_all_k(
    const float* __restrict__ cw2, const float* __restrict__ cw3,
    const float* __restrict__ cw4, const float* __restrict__ cw5,
    const float* __restrict__ cw6,
    ushort* __restrict__ bw2, ushort* __restrict__ bw3,
    ushort* __restrict__ bw4, ushort* __restrict__ bw5,
    ushort* __restrict__ bw6)
{
  int idx = blockIdx.x * 256 + threadIdx.x;
  if (idx < 6400)  { wprep_one(cw3, bw3, 32, 5, 64, idx); return; }
  idx -= 6400;
  if (idx < 25600) { wprep_one(cw4, bw4, 64, 5, 128, idx); return; }
  idx -= 25600;
  if (idx < 51200) { wprep_one(cw5, bw5, 128, 5, 128, idx); return; }
  idx -= 51200;
  if (idx < 18432) { wprep_one(cw6, bw6, 128, 3, 128, idx); return; }
  idx -= 18432;
  if (idx < 1024)  { wprep_one(cw2, bw2, 16, 4, 32, idx); }
}

// ---------------- fused linear weight pre-swizzle (lw1 + lw2 + wih, 1 launch) ----------------
__device__ __forceinline__ void wprep_lin_one(
    const float* __restrict__ w, ushort* __restrict__ bswz,
    int Kdim, int NT, int idx)
{
  const int lane = idx & 63;
  const int nt = (idx >> 6) % NT;
  const int ks = idx / (64 * NT);
  const int oc = nt * 16 + (lane & 15);
  const int kb = ks * 32 + (lane >> 4) * 8;
  ushort tmp[8];
#pragma unroll
  for (int j = 0; j < 8; ++j) tmp[j] = f2bf(w[(size_t)oc * Kdim + kb + j]);
  *(bhalf8*)(bswz + (size_t)idx * 8) = *(const bhalf8*)tmp;
}

__global__ __launch_bounds__(256) void wprep_lin3_k(
    const float* __restrict__ lw1, const float* __restrict__ lw2,
    const float* __restrict__ wih,
    ushort* __restrict__ bw1, ushort* __restrict__ bwl2,
    ushort* __restrict__ bwih)
{
  int idx = blockIdx.x * 256 + threadIdx.x;
  if (idx < 1048576) { wprep_lin_one(lw1, bw1, 8192, 64, idx); return; }
  idx -= 1048576;
  if (idx < 49152)   { wprep_lin_one(lw2, bwl2, 1024, 24, idx); return; }
  idx -= 49152;
  if (idx < 73728)   { wprep_lin_one(wih, bwih, 384, 96, idx); }
}

// ---------------- conv2 MFMA with in-register 2x2 maxpool — unchanged PASS ----------------
__global__ __launch_bounds__(256) void conv2mfma_k(
    const float* __restrict__ in, const ushort* __restrict__ bswz,
    const float* __restrict__ bias, float* __restrict__ out)
{
  constexpr int IC = 16, IH = 47, IW = 47;
  constexpr int NPIX = IH * IW;
  constexpr int ROWU = IC + 8;
  constexpr int KS = 8;
  __shared__ ushort imgT[NPIX * ROWU];
  const int b = blockIdx.x, tid = threadIdx.x;
  const int lane = tid & 63, wv = tid >> 6;

  for (int e = tid; e < IC * NPIX; e += 256) {
    const int ic = e / NPIX, pix = e % NPIX;
    imgT[pix * ROWU + ic] = f2bf(in[((size_t)b * IC + ic) * NPIX + pix]);
  }
  __syncthreads();

  const int col = lane & 15, g = lane >> 4;
  const float b0 = bias[col], b1 = bias[16 + col];

  for (int it = wv; it < 66; it += 4) {
    const int pyp = it / 3, tx = it - pyp * 3;
    int px = tx * 16 + col; px = px < 43 ? px : 43;
    floatx4 acc[2][2];
#pragma unroll
    for (int dy = 0; dy < 2; ++dy)
#pragma unroll
      for (int nt = 0; nt < 2; ++nt) acc[dy][nt] = (floatx4){0.f, 0.f, 0.f, 0.f};

    for (int ks = 0; ks < KS; ++ks) {
      bhalf8 bf[2];
#pragma unroll
      for (int nt = 0; nt < 2; ++nt)
        bf[nt] = *(const bhalf8*)(bswz + ((size_t)(ks * 2 + nt) * 64 + lane) * 8);
      const int kk = ks * 32 + g * 8;
      const int tap = kk >> 4, icb = kk & 15;
      const int ky = tap >> 2, kx = tap & 3;
      bhalf8 af[2];
#pragma unroll
      for (int dy = 0; dy < 2; ++dy)
        af[dy] = *(const bhalf8*)&imgT[((2 * pyp + dy + ky) * IW + px + kx) * ROWU + icb];
#pragma unroll
      for (int dy = 0; dy < 2; ++dy)
#pragma unroll
        for (int nt = 0; nt < 2; ++nt)
          acc[dy][nt] = __builtin_amdgcn_mfma_f32_16x16x32_bf16(
              af[dy], bf[nt], acc[dy][nt], 0, 0, 0);
    }
#pragma unroll
    for (int nt = 0; nt < 2; ++nt) {
      const int oc = nt * 16 + col;
      const float bb = nt ? b1 : b0;
      float vv[4];
#pragma unroll
      for (int i = 0; i < 4; ++i) vv[i] = fmaxf(acc[0][nt][i], acc[1][nt][i]);
#pragma unroll
      for (int q = 0; q < 2; ++q) {
        const int pxp = tx * 8 + g * 2 + q;
        if (pxp < 22) {
          const float v = fmaxf(fmaxf(vv[2 * q], vv[2 * q + 1]) + bb, 0.f);
          out[((size_t)b * 32 + oc) * 484 + pyp * 22 + pxp] = v;
        }
      }
    }
  }
}

// ---------------- MFMA implicit-GEMM conv (+bias+relu) — unchanged PASS ----------------
template <int IC, int IH, int IW, int KW_, int OC, int MC>
__global__ __launch_bounds__(256) void convmfma_k(
    const float* __restrict__ in, const ushort* __restrict__ bswz,
    const float* __restrict__ bias, float* __restrict__ out)
{
  constexpr int OH = IH - KW_ + 1, OW = IW - KW_ + 1, P = OH * OW;
  constexpr int NPIX = IH * IW;
  constexpr int KS = IC * KW_ * KW_ / 32;
  constexpr int NT = OC / 16;
  constexpr int NPW = NT / 4;
  constexpr int MT = (P + 15) / 16;
  constexpr int ROWU = IC + 8;
  static_assert(NT % 4 == 0 && IC % 32 == 0, "cfg");

  __shared__ ushort imgT[NPIX * ROWU];
  const int b = blockIdx.x, tid = threadIdx.x;
  const int lane = tid & 63, wv = tid >> 6;
  const int icoff = (lane >> 4) * 8;

  for (int e = tid; e < IC * NPIX; e += 256) {
    const int ic = e / NPIX, pix = e % NPIX;
    imgT[pix * ROWU + ic] = f2bf(in[((size_t)b * IC + ic) * NPIX + pix]);
  }
  __syncthreads();

  for (int m0 = 0; m0 < MT; m0 += MC) {
    floatx4 acc[MC][NPW];
#pragma unroll
    for (int mi = 0; mi < MC; ++mi)
#pragma unroll
      for (int nn = 0; nn < NPW; ++nn)
        acc[mi][nn] = (floatx4){0.f, 0.f, 0.f, 0.f};

    int pbase[MC];
#pragma unroll
    for (int mi = 0; mi < MC; ++mi) {
      int p = (m0 + mi) * 16 + (lane & 15);
      p = p < P ? p : P - 1;
      pbase[mi] = ((p / OW) * IW + (p % OW)) * ROWU;
    }

    bhalf8 bcur[NPW];
#pragma unroll
    for (int nn = 0; nn < NPW; ++nn)
      bcur[nn] = *(const bhalf8*)(bswz + ((size_t)(wv * NPW + nn) * 64 + lane) * 8);

    for (int ks = 0; ks < KS; ++ks) {
      bhalf8 bnext[NPW];
      if (ks + 1 < KS) {
#pragma unroll
        for (int nn = 0; nn < NPW; ++nn)
          bnext[nn] = *(const bhalf8*)(bswz +
              ((size_t)((ks + 1) * NT + wv * NPW + nn) * 64 + lane) * 8);
      }
      const int tap = (ks * 32) / IC;
      const int icb = (ks * 32) % IC;
      const int aoff = ((tap / KW_) * IW + (tap % KW_)) * ROWU + icb + icoff;
      bhalf8 af[MC];
#pragma unroll
      for (int mi = 0; mi < MC; ++mi)
        af[mi] = *(const bhalf8*)&imgT[pbase[mi] + aoff];
#pragma unroll
      for (int mi = 0; mi < MC; ++mi)
#pragma unroll
        for (int nn = 0; nn < NPW; ++nn)
          acc[mi][nn] = __builtin_amdgcn_mfma_f32_16x16x32_bf16(
              af[mi], bcur[nn], acc[mi][nn], 0, 0, 0);
      if (ks + 1 < KS) {
#pragma unroll
        for (int nn = 0; nn < NPW; ++nn) bcur[nn] = bnext[nn];
      }
    }
#pragma unroll
    for (int mi = 0; mi < MC; ++mi)
#pragma unroll
      for (int nn = 0; nn < NPW; ++nn) {
        const int oc = (wv * NPW + nn) * 16 + (lane & 15);
#pragma unroll
        for (int i = 0; i < 4; ++i) {
          const int p = (m0 + mi) * 16 + (lane >> 4) * 4 + i;
          if (p < P) {
            const float v = fmaxf(acc[mi][nn][i] + bias[oc], 0.f);
            out[((size_t)b * OC + oc) * P + p] = v;
          }
        }
      }
  }
}

// ---------------- bf16 MFMA GEMM v2: f32 A (converted in staging), ACT, b2 ----------------
// C[M,N] = act(A[M,K] @ Bswz^T + b1 (+b2)). BM=64,BN=64,BK=64, 256t/4 waves.
template <int ACT>
__global__ __launch_bounds__(256) void gemm_bf16_k(
    const float* __restrict__ A, const ushort* __restrict__ bswz,
    const float* __restrict__ b1, const float* __restrict__ b2,
    float* __restrict__ C, int M, int N, int K)
{
  __shared__ ushort As[64][72];
  const int bn = blockIdx.x, bm = blockIdx.y, tid = threadIdx.x;
  const int lane = tid & 63, wv = tid >> 6;
  const int m0 = bm * 64, n0 = bn * 64;
  const int NTg = N / 16;
  const int ntg = bn * 4 + wv;
  floatx4 acc[4];
#pragma unroll
  for (int mt = 0; mt < 4; ++mt) acc[mt] = (floatx4){0.f, 0.f, 0.f, 0.f};

  for (int kc = 0; kc < K / 64; ++kc) {
    __syncthreads();
#pragma unroll
    for (int q = 0; q < 2; ++q) {
      const int id = q * 256 + tid;
      const int row = id >> 3, kcol = (id & 7) * 8;
      const float* ap = &A[(size_t)(m0 + row) * K + kc * 64 + kcol];
      const float4 v0 = *(const float4*)ap;
      const float4 v1 = *(const float4*)(ap + 4);
      ushort t[8] = {f2bf(v0.x), f2bf(v0.y), f2bf(v0.z), f2bf(v0.w),
                     f2bf(v1.x), f2bf(v1.y), f2bf(v1.z), f2bf(v1.w)};
      *(bhalf8*)&As[row][kcol] = *(const bhalf8*)t;
    }
    __syncthreads();
#pragma unroll
    for (int k2 = 0; k2 < 2; ++k2) {
      const int ks = kc * 2 + k2;
      const bhalf8 bf = *(const bhalf8*)(bswz + ((size_t)(ks * NTg + ntg) * 64 + lane) * 8);
      const int ksub = k2 * 32 + (lane >> 4) * 8;
#pragma unroll
      for (int mt = 0; mt < 4; ++mt) {
        const bhalf8 af = *(const bhalf8*)&As[mt * 16 + (lane & 15)][ksub];
        acc[mt] = __builtin_amdgcn_mfma_f32_16x16x32_bf16(af, bf, acc[mt], 0, 0, 0);
      }
    }
  }
  const int n = n0 + wv * 16 + (lane & 15);
  const float bb = b1[n] + (b2 ? b2[n] : 0.f);
#pragma unroll
  for (int mt = 0; mt < 4; ++mt)
#pragma unroll
    for (int i = 0; i < 4; ++i) {
      const int m = m0 + mt * 16 + (lane >> 4) * 4 + i;
      float v = acc[mt][i] + bb;
      if (ACT == 1) v = 1.f / (1.f + expf(-v));
      C[(size_t)m * N + n] = v;
    }
}

// ---------------- persistent LSTM — R12 PASS + dual-accumulator dot ----------------
#define NWG 16
#define CPW 24
__global__ __launch_bounds__(768) void lstm_k(
    const float* __restrict__ gin, const float* __restrict__ whh,
    float* __restrict__ out, unsigned long long* __restrict__ tagged)
{
  __shared__ __align__(16) float hsm[8][52];
  __shared__ float gsum[96];
  const int wg = blockIdx.x, tid = threadIdx.x;
  const int r = tid >> 3, lk = tid & 7;
  const int gq = r / CPW, cl = r % CPW;
  const int grow = gq * 384 + wg * CPW + cl;
  float wreg[48];
  {
    const float* wr = whh + (size_t)grow * 384 + lk * 48;
#pragma unroll
    for (int i = 0; i < 48; ++i) wreg[i] = wr[i];
  }
  float c = 0.f;
  if (tid < 64) __builtin_amdgcn_s_setprio(1);  // wave0 = critical producer
  __syncthreads();
  for (int t = 0; t < 512; ++t) {
    float g0 = 0.f, g1 = 0.f, g2 = 0.f, g3 = 0.f;
    if (tid < CPW) {
      const int j = wg * CPW + tid;
      g0 = gin[(size_t)t * 1536 + 0 * 384 + j];
      g1 = gin[(size_t)t * 1536 + 1 * 384 + j];
      g2 = gin[(size_t)t * 1536 + 2 * 384 + j];
      g3 = gin[(size_t)t * 1536 + 3 * 384 + j];
    }
    if (tid < 384) {
      float hv;
      if (t == 0) {
        hv = 0.f;
      } else {
        unsigned long long u;
        do {
          u = __hip_atomic_load(&tagged[(size_t)(t - 1) * 384 + tid],
                                __ATOMIC_RELAXED, __HIP_MEMORY_SCOPE_AGENT);
        } while ((unsigned)(u >> 32) != (unsigned)t);
        union { unsigned ui; float f; } cv; cv.ui = (unsigned)u; hv = cv.f;
      }
      hsm[tid / 48][tid % 48] = hv;
    }
    __syncthreads();
    float s0 = 0.f, s1 = 0.f;  // dual acc: halves the FMA dep chain
    {
      const float4* hp = (const float4*)&hsm[lk][0];
#pragma unroll
      for (int q = 0; q < 12; q += 2) {
        const float4 ha = hp[q], hb = hp[q + 1];
        s0 += wreg[4 * q + 0] * ha.x + wreg[4 * q + 1] * ha.y
            + wreg[4 * q + 2] * ha.z + wreg[4 * q + 3] * ha.w;
        s1 += wreg[4 * q + 4] * hb.x + wreg[4 * q + 5] * hb.y
            + wreg[4 * q + 6] * hb.z + wreg[4 * q + 7] * hb.w;
      }
    }
    float s = s0 + s1;
    s += __shfl_xor(s, 1);
    s += __shfl_xor(s, 2);
    s += __shfl_xor(s, 4);
    if (lk == 0) gsum[r] = s;
    __syncthreads();
    if (tid < CPW) {
      const float gi = gsum[0 * CPW + tid] + g0;
      const float gf = gsum[1 * CPW + tid] + g1;
      const float gg = gsum[2 * CPW + tid] + g2;
      const float go = gsum[3 * CPW + tid] + g3;
      const float si = fsig(gi);
      const float sf = fsig(gf);
      const float so = fsig(go);
      c = sf * c + si * ftanh(gg);
      const float hn = so * ftanh(c);
      const int j = wg * CPW + tid;
      union { float f; unsigned ui; } cv; cv.f = hn;
      const unsigned long long pk = ((unsigned long long)(t + 1) << 32) | cv.ui;
      __hip_atomic_store(&tagged[(size_t)t * 384 + j], pk,
                         __ATOMIC_RELAXED, __HIP_MEMORY_SCOPE_AGENT);
      out[(size_t)t * 384 + j] = hn;
    }
    // no end-of-step barrier: staging(t+1) gated by the post-dot barrier above
  }
}

extern "C" void kernel_launch(void* const* d_in, const int* in_sizes, int n_in,
                              void* d_out, int out_size, void* d_ws, size_t ws_size,
                              hipStream_t stream)
{
  const float* x   = (const float*)d_in[0];
  const float* cw1 = (const float*)d_in[1];
  const float* cb1 = (const float*)d_in[2];
  const float* cw2 = (const float*)d_in[3];
  const float* cb2 = (const float*)d_in[4];
  const float* cw3 = (const float*)d_in[5];
  const float* cb3 = (const float*)d_in[6];
  const float* cw4 = (const float*)d_in[7];
  const float* cb4 = (const float*)d_in[8];
  const float* cw5 = (const float*)d_in[9];
  const float* cb5 = (const float*)d_in[10];
  const float* cw6 = (const float*)d_in[11];
  const float* cb6 = (const float*)d_in[12];
  const float* lw1 = (const float*)d_in[13];
  const float* lb1 = (const float*)d_in[14];
  const float* lw2 = (const float*)d_in[15];
  const float* lb2 = (const float*)d_in[16];
  const float* wih = (const float*)d_in[17];
  const float* whh = (const float*)d_in[18];
  const float* bih = (const float*)d_in[19];
  const float* bhh = (const float*)d_in[20];
  float* out = (float*)d_out;
  char* ws = (char*)d_ws;

  // workspace layout (R3-fixed, proven; total unchanged)
  float* bufA = (float*)(ws);                       // 72.4 MB conv ping
  float* bufB = (float*)(ws + 72384512);            // 51.4 MB conv pong
  float* l1o  = (float*)(ws + 123764736);           // 2 MB
  float* x2   = (float*)(ws + 125861888);
  float* gin  = (float*)(ws + 126648320);
  // conv bswz weights in l1o region (dead until linear1 output overwrites):
  ushort* bw3 = (ushort*)(ws + 123764736);
  ushort* bw4 = (ushort*)(ws + 123764736 + 102400);
  ushort* bw5 = (ushort*)(ws + 123764736 + 512000);
  ushort* bw6 = (ushort*)(ws + 123764736 + 1331200);
  ushort* bw2 = (ushort*)(ws + 123764736 + 1626112);
  // post-conv6 scratch inside then-dead bufA region:
  ushort* bw1  = (ushort*)(ws);                     // 16,777,216 B swizzled lw1
  unsigned long long* tagged = (unsigned long long*)(ws + 25165824);  // 1,572,864 B
  ushort* bwl2 = (ushort*)(ws + 26738688);          // 786,432 B swizzled lw2
  ushort* bwih = (ushort*)(ws + 27525120);          // 1,179,648 B swizzled wih

  // fused conv weight pre-swizzle: 6400+25600+51200+18432+1024 = 102656 items
  wprep_all_k<<<(102656 + 255) / 256, 256, 0, stream>>>(
      cw2, cw3, cw4, cw5, cw6, bw2, bw3, bw4, bw5, bw6);

  conv1_pool_k<<<512, 256, 0, stream>>>(x, cw1, cb1, bufA);
  conv2mfma_k<<<512, 256, 0, stream>>>(bufA, bw2, cb2, bufB);
  convmfma_k<32, 22, 22, 5, 64, 7><<<512, 256, 0, stream>>>(bufB, bw3, cb3, bufA);
  convmfma_k<64, 18, 18, 5, 128, 7><<<512, 256, 0, stream>>>(bufA, bw4, cb4, bufB);
  convmfma_k<128, 14, 14, 5, 128, 7><<<512, 256, 0, stream>>>(bufB, bw5, cb5, bufA);
  convmfma_k<128, 10, 10, 3, 128, 4><<<512, 256, 0, stream>>>(bufA, bw6, cb6, bufB);
  // bufA now dead -> linear weights + tagged live there
  // fused linear weight pre-swizzle: 1048576 + 49152 + 73728 = 1171456 items
  wprep_lin3_k<<<(1171456 + 255) / 256, 256, 0, stream>>>(
      lw1, lw2, wih, bw1, bwl2, bwih);
  hipMemsetAsync(tagged, 0, 512 * 384 * 8, stream);
  // tail GEMMs, all bf16-MFMA with in-staging f32->bf16 conversion
  gemm_bf16_k<0><<<dim3(16, 8), 256, 0, stream>>>(bufB, bw1, lb1, nullptr, l1o, 512, 1024, 8192);
  gemm_bf16_k<1><<<dim3(6, 8), 256, 0, stream>>>(l1o, bwl2, lb2, nullptr, x2, 512, 384, 1024);
  gemm_bf16_k<0><<<dim3(24, 8), 256, 0, stream>>>(x2, bwih, bih, bhh, gin, 512, 1536, 384);
  lstm_k<<<NWG, 768, 0, stream>>>(gin, whh, out, tagged);
}

// Round 16
// 1345.647 us; speedup vs baseline: 1.4624x; 1.0562x over previous
//
#include <hip/hip_runtime.h>
#include <cstddef>
#include <cstdint>

#define T256 256

typedef __attribute__((ext_vector_type(8))) short bhalf8;
typedef __attribute__((ext_vector_type(4))) float floatx4;

__device__ __forceinline__ ushort f2bf(float f) {
  union { float f; uint32_t u; } v; v.f = f;
  return (ushort)((v.u + 0x7fffu + ((v.u >> 16) & 1u)) >> 16);
}

// fast gate activations: v_exp_f32-based, overflow-safe
__device__ __forceinline__ float fsig(float x) {
  return 1.f / (1.f + __expf(-x));
}
__device__ __forceinline__ float ftanh(float x) {
  const float e = __expf(-2.f * fabsf(x));
  const float r = (1.f - e) / (1.f + e);
  return copysignf(r, x);
}

// ---------------- conv1 MFMA (1->16, 7x7, relu, pool2) — R16 NEW ----------------
// K-order k=ky*8+kx (49->64 padded, zero weights). A-frag = 8 consecutive kx
// = row segment img[row][px..px+7]. Dual-parity LDS copies (imgO shifted by 1)
// make every frag 4x ds_read_b32, always 4B-aligned. Pool fused (conv2 pattern):
// conv 94x94 padded to 96 cols = 6 tiles; vertical dy-pair accs; hmax pairs.
__global__ __launch_bounds__(256) void conv1mfma_k(
    const float* __restrict__ x, const ushort* __restrict__ bswz,
    const float* __restrict__ bias, float* __restrict__ out)
{
  constexpr int W = 104;   // padded LDS row width (u16)
  constexpr int R = 101;   // rows incl. pad row 100 (ky=7 reads, zero weights)
  __shared__ __align__(16) ushort imgE[R * W];
  __shared__ __align__(16) ushort imgO[R * W];  // imgO[r][c] = orig[r][c+1]
  const int b = blockIdx.x, tid = threadIdx.x;
  const int lane = tid & 63, wv = tid >> 6;
  const int col = lane & 15, g = lane >> 4;

  // zero everything (pad cols/rows MUST be 0: bf16 garbage could be NaN; NaN*0=NaN)
  for (int i = tid; i < R * W; i += 256) { imgE[i] = 0; imgO[i] = 0; }
  __syncthreads();
  for (int i = tid; i < 10000; i += 256) {
    const int r = i / 100, c = i % 100;
    const ushort v = f2bf(x[(size_t)b * 10000 + i]);
    imgE[r * W + c] = v;
    if (c >= 1) imgO[r * W + (c - 1)] = v;
  }
  __syncthreads();

  // B-frags: KS=2, NT=1 (16 oc)
  const bhalf8 bf0 = *(const bhalf8*)(bswz + ((size_t)lane) * 8);
  const bhalf8 bf1 = *(const bhalf8*)(bswz + ((size_t)(64 + lane)) * 8);
  const float bb = bias[col];

  for (int it = wv; it < 47 * 6; it += 4) {
    const int pyp = it / 6, tx = it % 6;
    int px = tx * 16 + col; px = px < 93 ? px : 93;  // clamp pad cols (outputs guarded)
    floatx4 acc[2];
    acc[0] = (floatx4){0.f, 0.f, 0.f, 0.f};
    acc[1] = (floatx4){0.f, 0.f, 0.f, 0.f};
#pragma unroll
    for (int ks = 0; ks < 2; ++ks) {
      const int ky = ks * 4 + g;
#pragma unroll
      for (int dy = 0; dy < 2; ++dy) {
        const int row = 2 * pyp + dy + ky;   // max 2*46+1+7 = 100 (pad row, w=0)
        const ushort* rowp = (px & 1) ? &imgO[row * W + px - 1] : &imgE[row * W + px];
        union { uint32_t u[4]; bhalf8 v; } cvt;
        cvt.u[0] = *(const uint32_t*)(rowp + 0);
        cvt.u[1] = *(const uint32_t*)(rowp + 2);
        cvt.u[2] = *(const uint32_t*)(rowp + 4);
        cvt.u[3] = *(const uint32_t*)(rowp + 6);
        acc[dy] = __builtin_amdgcn_mfma_f32_16x16x32_bf16(
            cvt.v, ks ? bf1 : bf0, acc[dy], 0, 0, 0);
      }
    }
    float vv[4];
#pragma unroll
    for (int i = 0; i < 4; ++i) vv[i] = fmaxf(acc[0][i], acc[1][i]);
#pragma unroll
    for (int q = 0; q < 2; ++q) {
      const int pxp = tx * 8 + g * 2 + q;
      if (pxp < 47) {
        const float v = fmaxf(fmaxf(vv[2 * q], vv[2 * q + 1]) + bb, 0.f);
        out[((size_t)b * 16 + col) * 2209 + pyp * 47 + pxp] = v;
      }
    }
  }
}

// ---------------- fused conv weight pre-swizzle (+conv1 range) ----------------
__device__ __forceinline__ void wprep_one(
    const float* __restrict__ w, ushort* __restrict__ bswz,
    int IC, int KW, int OC, int idx)
{
  const int NT = OC / 16;
  const int lane = idx & 63;
  const int nt = (idx >> 6) % NT;
  const int ks = idx / (64 * NT);
  const int oc = nt * 16 + (lane & 15);
  const int kb = ks * 32 + (lane >> 4) * 8;
  ushort tmp[8];
#pragma unroll
  for (int j = 0; j < 8; ++j) {
    const int k = kb + j;
    const int ic = k % IC, tap = k / IC;
    tmp[j] = f2bf(w[((size_t)oc * IC + ic) * (KW * KW) + tap]);
  }
  *(bhalf8*)(bswz + (size_t)idx * 8) = *(const bhalf8*)tmp;
}

__global__ __launch_bounds__(256) void wprep_all_k(
    const float* __restrict__ cw1, const float* __restrict__ cw2,
    const float* __restrict__ cw3, const float* __restrict__ cw4,
    const float* __restrict__ cw5, const float* __restrict__ cw6,
    ushort* __restrict__ bw1c, ushort* __restrict__ bw2,
    ushort* __restrict__ bw3, ushort* __restrict__ bw4,
    ushort* __restrict__ bw5, ushort* __restrict__ bw6)
{
  int idx = blockIdx.x * 256 + threadIdx.x;
  if (idx < 6400)  { wprep_one(cw3, bw3, 32, 5, 64, idx); return; }
  idx -= 6400;
  if (idx < 25600) { wprep_one(cw4, bw4, 64, 5, 128, idx); return; }
  idx -= 25600;
  if (idx < 51200) { wprep_one(cw5, bw5, 128, 5, 128, idx); return; }
  idx -= 51200;
  if (idx < 18432) { wprep_one(cw6, bw6, 128, 3, 128, idx); return; }
  idx -= 18432;
  if (idx < 1024)  { wprep_one(cw2, bw2, 16, 4, 32, idx); return; }
  idx -= 1024;
  if (idx < 128) {
    // conv1: k = ky*8+kx (kx 7->8 pad, ky 7->8 pad); KS=2, NT=1, OC=16
    const int lane = idx & 63;
    const int ks = idx >> 6;
    const int oc = lane & 15;
    const int kb = ks * 32 + (lane >> 4) * 8;
    ushort tmp[8];
#pragma unroll
    for (int j = 0; j < 8; ++j) {
      const int k = kb + j;
      const int ky = k >> 3, kx = k & 7;
      tmp[j] = (ky < 7 && kx < 7) ? f2bf(cw1[oc * 49 + ky * 7 + kx]) : (ushort)0;
    }
    *(bhalf8*)(bw1c + (size_t)idx * 8) = *(const bhalf8*)tmp;
  }
}

// ---------------- fused linear weight pre-swizzle (lw1 + lw2 + wih) ----------------
__device__ __forceinline__ void wprep_lin_one(
    const float* __restrict__ w, ushort* __restrict__ bswz,
    int Kdim, int NT, int idx)
{
  const int lane = idx & 63;
  const int nt = (idx >> 6) % NT;
  const int ks = idx / (64 * NT);
  const int oc = nt * 16 + (lane & 15);
  const int kb = ks * 32 + (lane >> 4) * 8;
  ushort tmp[8];
#pragma unroll
  for (int j = 0; j < 8; ++j) tmp[j] = f2bf(w[(size_t)oc * Kdim + kb + j]);
  *(bhalf8*)(bswz + (size_t)idx * 8) = *(const bhalf8*)tmp;
}

__global__ __launch_bounds__(256) void wprep_lin3_k(
    const float* __restrict__ lw1, const float* __restrict__ lw2,
    const float* __restrict__ wih,
    ushort* __restrict__ bw1, ushort* __restrict__ bwl2,
    ushort* __restrict__ bwih)
{
  int idx = blockIdx.x * 256 + threadIdx.x;
  if (idx < 1048576) { wprep_lin_one(lw1, bw1, 8192, 64, idx); return; }
  idx -= 1048576;
  if (idx < 49152)   { wprep_lin_one(lw2, bwl2, 1024, 24, idx); return; }
  idx -= 49152;
  if (idx < 73728)   { wprep_lin_one(wih, bwih, 384, 96, idx); }
}

// ---------------- conv2 MFMA with in-register 2x2 maxpool — unchanged PASS ----------------
__global__ __launch_bounds__(256) void conv2mfma_k(
    const float* __restrict__ in, const ushort* __restrict__ bswz,
    const float* __restrict__ bias, float* __restrict__ out)
{
  constexpr int IC = 16, IH = 47, IW = 47;
  constexpr int NPIX = IH * IW;
  constexpr int ROWU = IC + 8;
  constexpr int KS = 8;
  __shared__ ushort imgT[NPIX * ROWU];
  const int b = blockIdx.x, tid = threadIdx.x;
  const int lane = tid & 63, wv = tid >> 6;

  for (int e = tid; e < IC * NPIX; e += 256) {
    const int ic = e / NPIX, pix = e % NPIX;
    imgT[pix * ROWU + ic] = f2bf(in[((size_t)b * IC + ic) * NPIX + pix]);
  }
  __syncthreads();

  const int col = lane & 15, g = lane >> 4;
  const float b0 = bias[col], b1 = bias[16 + col];

  for (int it = wv; it < 66; it += 4) {
    const int pyp = it / 3, tx = it - pyp * 3;
    int px = tx * 16 + col; px = px < 43 ? px : 43;
    floatx4 acc[2][2];
#pragma unroll
    for (int dy = 0; dy < 2; ++dy)
#pragma unroll
      for (int nt = 0; nt < 2; ++nt) acc[dy][nt] = (floatx4){0.f, 0.f, 0.f, 0.f};

    for (int ks = 0; ks < KS; ++ks) {
      bhalf8 bf[2];
#pragma unroll
      for (int nt = 0; nt < 2; ++nt)
        bf[nt] = *(const bhalf8*)(bswz + ((size_t)(ks * 2 + nt) * 64 + lane) * 8);
      const int kk = ks * 32 + g * 8;
      const int tap = kk >> 4, icb = kk & 15;
      const int ky = tap >> 2, kx = tap & 3;
      bhalf8 af[2];
#pragma unroll
      for (int dy = 0; dy < 2; ++dy)
        af[dy] = *(const bhalf8*)&imgT[((2 * pyp + dy + ky) * IW + px + kx) * ROWU + icb];
#pragma unroll
      for (int dy = 0; dy < 2; ++dy)
#pragma unroll
        for (int nt = 0; nt < 2; ++nt)
          acc[dy][nt] = __builtin_amdgcn_mfma_f32_16x16x32_bf16(
              af[dy], bf[nt], acc[dy][nt], 0, 0, 0);
    }
#pragma unroll
    for (int nt = 0; nt < 2; ++nt) {
      const int oc = nt * 16 + col;
      const float bb = nt ? b1 : b0;
      float vv[4];
#pragma unroll
      for (int i = 0; i < 4; ++i) vv[i] = fmaxf(acc[0][nt][i], acc[1][nt][i]);
#pragma unroll
      for (int q = 0; q < 2; ++q) {
        const int pxp = tx * 8 + g * 2 + q;
        if (pxp < 22) {
          const float v = fmaxf(fmaxf(vv[2 * q], vv[2 * q + 1]) + bb, 0.f);
          out[((size_t)b * 32 + oc) * 484 + pyp * 22 + pxp] = v;
        }
      }
    }
  }
}

// ---------------- MFMA implicit-GEMM conv (+bias+relu) — unchanged PASS ----------------
template <int IC, int IH, int IW, int KW_, int OC, int MC>
__global__ __launch_bounds__(256) void convmfma_k(
    const float* __restrict__ in, const ushort* __restrict__ bswz,
    const float* __restrict__ bias, float* __restrict__ out)
{
  constexpr int OH = IH - KW_ + 1, OW = IW - KW_ + 1, P = OH * OW;
  constexpr int NPIX = IH * IW;
  constexpr int KS = IC * KW_ * KW_ / 32;
  constexpr int NT = OC / 16;
  constexpr int NPW = NT / 4;
  constexpr int MT = (P + 15) / 16;
  constexpr int ROWU = IC + 8;
  static_assert(NT % 4 == 0 && IC % 32 == 0, "cfg");

  __shared__ ushort imgT[NPIX * ROWU];
  const int b = blockIdx.x, tid = threadIdx.x;
  const int lane = tid & 63, wv = tid >> 6;
  const int icoff = (lane >> 4) * 8;

  for (int e = tid; e < IC * NPIX; e += 256) {
    const int ic = e / NPIX, pix = e % NPIX;
    imgT[pix * ROWU + ic] = f2bf(in[((size_t)b * IC + ic) * NPIX + pix]);
  }
  __syncthreads();

  for (int m0 = 0; m0 < MT; m0 += MC) {
    floatx4 acc[MC][NPW];
#pragma unroll
    for (int mi = 0; mi < MC; ++mi)
#pragma unroll
      for (int nn = 0; nn < NPW; ++nn)
        acc[mi][nn] = (floatx4){0.f, 0.f, 0.f, 0.f};

    int pbase[MC];
#pragma unroll
    for (int mi = 0; mi < MC; ++mi) {
      int p = (m0 + mi) * 16 + (lane & 15);
      p = p < P ? p : P - 1;
      pbase[mi] = ((p / OW) * IW + (p % OW)) * ROWU;
    }

    bhalf8 bcur[NPW];
#pragma unroll
    for (int nn = 0; nn < NPW; ++nn)
      bcur[nn] = *(const bhalf8*)(bswz + ((size_t)(wv * NPW + nn) * 64 + lane) * 8);

    for (int ks = 0; ks < KS; ++ks) {
      bhalf8 bnext[NPW];
      if (ks + 1 < KS) {
#pragma unroll
        for (int nn = 0; nn < NPW; ++nn)
          bnext[nn] = *(const bhalf8*)(bswz +
              ((size_t)((ks + 1) * NT + wv * NPW + nn) * 64 + lane) * 8);
      }
      const int tap = (ks * 32) / IC;
      const int icb = (ks * 32) % IC;
      const int aoff = ((tap / KW_) * IW + (tap % KW_)) * ROWU + icb + icoff;
      bhalf8 af[MC];
#pragma unroll
      for (int mi = 0; mi < MC; ++mi)
        af[mi] = *(const bhalf8*)&imgT[pbase[mi] + aoff];
#pragma unroll
      for (int mi = 0; mi < MC; ++mi)
#pragma unroll
        for (int nn = 0; nn < NPW; ++nn)
          acc[mi][nn] = __builtin_amdgcn_mfma_f32_16x16x32_bf16(
              af[mi], bcur[nn], acc[mi][nn], 0, 0, 0);
      if (ks + 1 < KS) {
#pragma unroll
        for (int nn = 0; nn < NPW; ++nn) bcur[nn] = bnext[nn];
      }
    }
#pragma unroll
    for (int mi = 0; mi < MC; ++mi)
#pragma unroll
      for (int nn = 0; nn < NPW; ++nn) {
        const int oc = (wv * NPW + nn) * 16 + (lane & 15);
#pragma unroll
        for (int i = 0; i < 4; ++i) {
          const int p = (m0 + mi) * 16 + (lane >> 4) * 4 + i;
          if (p < P) {
            const float v = fmaxf(acc[mi][nn][i] + bias[oc], 0.f);
            out[((size_t)b * OC + oc) * P + p] = v;
          }
        }
      }
  }
}

// ---------------- bf16 MFMA GEMM v2 (f32 A converted in staging, ACT, b2) ----------------
template <int ACT>
__global__ __launch_bounds__(256) void gemm_bf16_k(
    const float* __restrict__ A, const ushort* __restrict__ bswz,
    const float* __restrict__ b1, const float* __restrict__ b2,
    float* __restrict__ C, int M, int N, int K)
{
  __shared__ ushort As[64][72];
  const int bn = blockIdx.x, bm = blockIdx.y, tid = threadIdx.x;
  const int lane = tid & 63, wv = tid >> 6;
  const int m0 = bm * 64, n0 = bn * 64;
  const int NTg = N / 16;
  const int ntg = bn * 4 + wv;
  floatx4 acc[4];
#pragma unroll
  for (int mt = 0; mt < 4; ++mt) acc[mt] = (floatx4){0.f, 0.f, 0.f, 0.f};

  for (int kc = 0; kc < K / 64; ++kc) {
    __syncthreads();
#pragma unroll
    for (int q = 0; q < 2; ++q) {
      const int id = q * 256 + tid;
      const int row = id >> 3, kcol = (id & 7) * 8;
      const float* ap = &A[(size_t)(m0 + row) * K + kc * 64 + kcol];
      const float4 v0 = *(const float4*)ap;
      const float4 v1 = *(const float4*)(ap + 4);
      ushort t[8] = {f2bf(v0.x), f2bf(v0.y), f2bf(v0.z), f2bf(v0.w),
                     f2bf(v1.x), f2bf(v1.y), f2bf(v1.z), f2bf(v1.w)};
      *(bhalf8*)&As[row][kcol] = *(const bhalf8*)t;
    }
    __syncthreads();
#pragma unroll
    for (int k2 = 0; k2 < 2; ++k2) {
      const int ks = kc * 2 + k2;
      const bhalf8 bf = *(const bhalf8*)(bswz + ((size_t)(ks * NTg + ntg) * 64 + lane) * 8);
      const int ksub = k2 * 32 + (lane >> 4) * 8;
#pragma unroll
      for (int mt = 0; mt < 4; ++mt) {
        const bhalf8 af = *(const bhalf8*)&As[mt * 16 + (lane & 15)][ksub];
        acc[mt] = __builtin_amdgcn_mfma_f32_16x16x32_bf16(af, bf, acc[mt], 0, 0, 0);
      }
    }
  }
  const int n = n0 + wv * 16 + (lane & 15);
  const float bb = b1[n] + (b2 ? b2[n] : 0.f);
#pragma unroll
  for (int mt = 0; mt < 4; ++mt)
#pragma unroll
    for (int i = 0; i < 4; ++i) {
      const int m = m0 + mt * 16 + (lane >> 4) * 4 + i;
      float v = acc[mt][i] + bb;
      if (ACT == 1) v = 1.f / (1.f + expf(-v));
      C[(size_t)m * N + n] = v;
    }
}

// ---------------- persistent LSTM — unchanged R15 PASS ----------------
#define NWG 16
#define CPW 24
__global__ __launch_bounds__(768) void lstm_k(
    const float* __restrict__ gin, const float* __restrict__ whh,
    float* __restrict__ out, unsigned long long* __restrict__ tagged)
{
  __shared__ __align__(16) float hsm[8][52];
  __shared__ float gsum[96];
  const int wg = blockIdx.x, tid = threadIdx.x;
  const int r = tid >> 3, lk = tid & 7;
  const int gq = r / CPW, cl = r % CPW;
  const int grow = gq * 384 + wg * CPW + cl;
  float wreg[48];
  {
    const float* wr = whh + (size_t)grow * 384 + lk * 48;
#pragma unroll
    for (int i = 0; i < 48; ++i) wreg[i] = wr[i];
  }
  float c = 0.f;
  if (tid < 64) __builtin_amdgcn_s_setprio(1);  // wave0 = critical producer
  __syncthreads();
  for (int t = 0; t < 512; ++t) {
    float g0 = 0.f, g1 = 0.f, g2 = 0.f, g3 = 0.f;
    if (tid < CPW) {
      const int j = wg * CPW + tid;
      g0 = gin[(size_t)t * 1536 + 0 * 384 + j];
      g1 = gin[(size_t)t * 1536 + 1 * 384 + j];
      g2 = gin[(size_t)t * 1536 + 2 * 384 + j];
      g3 = gin[(size_t)t * 1536 + 3 * 384 + j];
    }
    if (tid < 384) {
      float hv;
      if (t == 0) {
        hv = 0.f;
      } else {
        unsigned long long u;
        do {
          u = __hip_atomic_load(&tagged[(size_t)(t - 1) * 384 + tid],
                                __ATOMIC_RELAXED, __HIP_MEMORY_SCOPE_AGENT);
        } while ((unsigned)(u >> 32) != (unsigned)t);
        union { unsigned ui; float f; } cv; cv.ui = (unsigned)u; hv = cv.f;
      }
      hsm[tid / 48][tid % 48] = hv;
    }
    __syncthreads();
    float s0 = 0.f, s1 = 0.f;
    {
      const float4* hp = (const float4*)&hsm[lk][0];
#pragma unroll
      for (int q = 0; q < 12; q += 2) {
        const float4 ha = hp[q], hb = hp[q + 1];
        s0 += wreg[4 * q + 0] * ha.x + wreg[4 * q + 1] * ha.y
            + wreg[4 * q + 2] * ha.z + wreg[4 * q + 3] * ha.w;
        s1 += wreg[4 * q + 4] * hb.x + wreg[4 * q + 5] * hb.y
            + wreg[4 * q + 6] * hb.z + wreg[4 * q + 7] * hb.w;
      }
    }
    float s = s0 + s1;
    s += __shfl_xor(s, 1);
    s += __shfl_xor(s, 2);
    s += __shfl_xor(s, 4);
    if (lk == 0) gsum[r] = s;
    __syncthreads();
    if (tid < CPW) {
      const float gi = gsum[0 * CPW + tid] + g0;
      const float gf = gsum[1 * CPW + tid] + g1;
      const float gg = gsum[2 * CPW + tid] + g2;
      const float go = gsum[3 * CPW + tid] + g3;
      const float si = fsig(gi);
      const float sf = fsig(gf);
      const float so = fsig(go);
      c = sf * c + si * ftanh(gg);
      const float hn = so * ftanh(c);
      const int j = wg * CPW + tid;
      union { float f; unsigned ui; } cv; cv.f = hn;
      const unsigned long long pk = ((unsigned long long)(t + 1) << 32) | cv.ui;
      __hip_atomic_store(&tagged[(size_t)t * 384 + j], pk,
                         __ATOMIC_RELAXED, __HIP_MEMORY_SCOPE_AGENT);
      out[(size_t)t * 384 + j] = hn;
    }
    // no end-of-step barrier: staging(t+1) gated by the post-dot barrier above
  }
}

extern "C" void kernel_launch(void* const* d_in, const int* in_sizes, int n_in,
                              void* d_out, int out_size, void* d_ws, size_t ws_size,
                              hipStream_t stream)
{
  const float* x   = (const float*)d_in[0];
  const float* cw1 = (const float*)d_in[1];
  const float* cb1 = (const float*)d_in[2];
  const float* cw2 = (const float*)d_in[3];
  const float* cb2 = (const float*)d_in[4];
  const float* cw3 = (const float*)d_in[5];
  const float* cb3 = (const float*)d_in[6];
  const float* cw4 = (const float*)d_in[7];
  const float* cb4 = (const float*)d_in[8];
  const float* cw5 = (const float*)d_in[9];
  const float* cb5 = (const float*)d_in[10];
  const float* cw6 = (const float*)d_in[11];
  const float* cb6 = (const float*)d_in[12];
  const float* lw1 = (const float*)d_in[13];
  const float* lb1 = (const float*)d_in[14];
  const float* lw2 = (const float*)d_in[15];
  const float* lb2 = (const float*)d_in[16];
  const float* wih = (const float*)d_in[17];
  const float* whh = (const float*)d_in[18];
  const float* bih = (const float*)d_in[19];
  const float* bhh = (const float*)d_in[20];
  float* out = (float*)d_out;
  char* ws = (char*)d_ws;

  // workspace layout (R3-fixed, proven; total unchanged)
  float* bufA = (float*)(ws);                       // 72.4 MB conv ping
  float* bufB = (float*)(ws + 72384512);            // 51.4 MB conv pong
  float* l1o  = (float*)(ws + 123764736);           // 2 MB
  float* x2   = (float*)(ws + 125861888);
  float* gin  = (float*)(ws + 126648320);
  // conv bswz weights in l1o region (dead until linear1 output overwrites):
  ushort* bw3 = (ushort*)(ws + 123764736);
  ushort* bw4 = (ushort*)(ws + 123764736 + 102400);
  ushort* bw5 = (ushort*)(ws + 123764736 + 512000);
  ushort* bw6 = (ushort*)(ws + 123764736 + 1331200);
  ushort* bw2 = (ushort*)(ws + 123764736 + 1626112);
  ushort* bw1c = (ushort*)(ws + 123764736 + 1642496);  // 2,048 B conv1 weights
  // post-conv6 scratch inside then-dead bufA region:
  ushort* bw1  = (ushort*)(ws);                     // 16,777,216 B swizzled lw1
  unsigned long long* tagged = (unsigned long long*)(ws + 25165824);  // 1,572,864 B
  ushort* bwl2 = (ushort*)(ws + 26738688);          // 786,432 B swizzled lw2
  ushort* bwih = (ushort*)(ws + 27525120);          // 1,179,648 B swizzled wih

  // fused conv weight pre-swizzle: 6400+25600+51200+18432+1024+128 = 102784 items
  wprep_all_k<<<(102784 + 255) / 256, 256, 0, stream>>>(
      cw1, cw2, cw3, cw4, cw5, cw6, bw1c, bw2, bw3, bw4, bw5, bw6);

  conv1mfma_k<<<512, 256, 0, stream>>>(x, bw1c, cb1, bufA);
  conv2mfma_k<<<512, 256, 0, stream>>>(bufA, bw2, cb2, bufB);
  convmfma_k<32, 22, 22, 5, 64, 7><<<512, 256, 0, stream>>>(bufB, bw3, cb3, bufA);
  convmfma_k<64, 18, 18, 5, 128, 7><<<512, 256, 0, stream>>>(bufA, bw4, cb4, bufB);
  convmfma_k<128, 14, 14, 5, 128, 7><<<512, 256, 0, stream>>>(bufB, bw5, cb5, bufA);
  convmfma_k<128, 10, 10, 3, 128, 4><<<512, 256, 0, stream>>>(bufA, bw6, cb6, bufB);
  // bufA now dead -> linear weights + tagged live there
  wprep_lin3_k<<<(1171456 + 255) / 256, 256, 0, stream>>>(
      lw1, lw2, wih, bw1, bwl2, bwih);
  hipMemsetAsync(tagged, 0, 512 * 384 * 8, stream);
  gemm_bf16_k<0><<<dim3(16, 8), 256, 0, stream>>>(bufB, bw1, lb1, nullptr, l1o, 512, 1024, 8192);
  gemm_bf16_k<1><<<dim3(6, 8), 256, 0, stream>>>(l1o, bwl2, lb2, nullptr, x2, 512, 384, 1024);
  gemm_bf16_k<0><<<dim3(24, 8), 256, 0, stream>>>(x2, bwih, bih, bhh, gin, 512, 1536, 384);
  lstm_k<<<NWG, 768, 0, stream>>>(gin, whh, out, tagged);
}